// Round 18
// baseline (597.164 us; speedup 1.0000x reference)
//
#include <hip/hip_runtime.h>

#define LNUM 6
#define CH 192
#define FCH 768
#define NH 2
#define DKH 96
#define WIN 4
#define BATCH 4
#define TLEN 2048
#define EPSV 1e-5f
#define SCH 4
#define CHUNK (TLEN / SCH)
#define NBCT (BATCH*CH*TLEN)
#define NBFT (BATCH*FCH*TLEN)
#define BHT (BATCH*NH*TLEN)    // 16384

typedef __attribute__((ext_vector_type(8))) short bf16x8;
typedef __attribute__((ext_vector_type(4))) float f32x4;
typedef __attribute__((ext_vector_type(8))) unsigned short u16x8;

__device__ __forceinline__ unsigned short f2bf(float f) {
  unsigned int u = __builtin_bit_cast(unsigned int, f);
  u = (u + 0x7fffu + ((u >> 16) & 1u)) >> 16;
  return (unsigned short)u;
}
__device__ __forceinline__ float bf2f(unsigned short s) {
  return __builtin_bit_cast(float, ((unsigned int)s) << 16);
}
__device__ __forceinline__ float exp2a(float x) {   // hardware 2^x, hazard-safe
#if __has_builtin(__builtin_amdgcn_exp2f)
  return __builtin_amdgcn_exp2f(x);
#else
  return exp2f(x);
#endif
}

// ---------- fused weight prep (QKV fuse+scale, WO cvt, FFN w1/w2 transpose) ----------
__global__ __launch_bounds__(256) void prep_all(
    const float* __restrict__ wq, const float* __restrict__ wk, const float* __restrict__ wv,
    const float* __restrict__ bq, const float* __restrict__ bk, const float* __restrict__ bv,
    const float* __restrict__ wo, const float* __restrict__ fw1, const float* __restrict__ fw2,
    unsigned short* __restrict__ Wqkv, float* __restrict__ Bqkv,
    unsigned short* __restrict__ Wob, unsigned short* __restrict__ W1b,
    unsigned short* __restrict__ W2b)
{
  const float qscale = 0.10206207261596575f * 1.4426950408889634f;  // dk^-0.5 * log2(e)
  const int n0 = LNUM * 576 * CH;            // qkv
  const int n1 = LNUM * CH * CH;             // wo
  const int n2 = LNUM * 3 * FCH * CH;        // w1
  const int n3 = LNUM * 3 * CH * FCH;        // w2
  int total = n0 + n1 + n2 + n3;
  for (int i = blockIdx.x * 256 + threadIdx.x; i < total; i += gridDim.x * 256) {
    if (i < n0) {
      int c = i % CH; int n = (i / CH) % 576; int l = i / (CH * 576);
      float sc = (n < 192) ? qscale : 1.f;
      const float* src = (n < 192) ? wq : (n < 384) ? wk : wv;
      int nn = n % 192;
      Wqkv[i] = f2bf(src[((size_t)l * CH + nn) * CH + c] * sc);
      if (c == 0) {
        const float* bs = (n < 192) ? bq : (n < 384) ? bk : bv;
        Bqkv[l * 576 + n] = bs[l * CH + nn] * sc;
      }
    } else if (i < n0 + n1) {
      int j = i - n0;
      Wob[j] = f2bf(wo[j]);
    } else if (i < n0 + n1 + n2) {
      int j = i - n0 - n1;           // dst [L][3][FCH][CH]
      int c = j % CH; int t1 = j / CH;
      int f = t1 % FCH; int t2 = t1 / FCH;
      int kk = t2 % 3; int l = t2 / 3;
      W1b[j] = f2bf(fw1[(((size_t)l * FCH + f) * CH + c) * 3 + kk]);
    } else {
      int j = i - n0 - n1 - n2;      // dst [L][3][CH][FCH]
      int c = j % FCH; int t1 = j / FCH;
      int f = t1 % CH; int t2 = t1 / CH;
      int kk = t2 % 3; int l = t2 / 3;
      W2b[j] = f2bf(fw2[(((size_t)l * CH + f) * FCH + c) * 3 + kk]);
    }
  }
}

// ---------- transpose in/out ----------
__global__ __launch_bounds__(256) void tin_kernel(const float* __restrict__ x,
    const float* __restrict__ mask, float* __restrict__ Xc, unsigned short* __restrict__ Xbf) {
  __shared__ float ls[32][33];
  int b = blockIdx.z; int c0 = blockIdx.y * 32, t0 = blockIdx.x * 32;
  int tx = threadIdx.x & 31, ty = threadIdx.x >> 5;
  #pragma unroll
  for (int j = 0; j < 4; ++j)
    ls[ty + j * 8][tx] = x[((size_t)b * CH + c0 + ty + j * 8) * TLEN + t0 + tx];
  __syncthreads();
  #pragma unroll
  for (int j = 0; j < 4; ++j) {
    int t = t0 + ty + j * 8;
    float v = ls[tx][ty + j * 8] * mask[b * TLEN + t];
    size_t o = ((size_t)b * TLEN + t) * CH + c0 + tx;
    Xc[o] = v; Xbf[o] = f2bf(v);
  }
}

__global__ __launch_bounds__(256) void tout_kernel(const float* __restrict__ Xc,
    const float* __restrict__ mask, float* __restrict__ out) {
  __shared__ float ls[32][33];
  int b = blockIdx.z; int c0 = blockIdx.y * 32, t0 = blockIdx.x * 32;
  int tx = threadIdx.x & 31, ty = threadIdx.x >> 5;
  #pragma unroll
  for (int j = 0; j < 4; ++j)
    ls[ty + j * 8][tx] = Xc[((size_t)b * TLEN + t0 + ty + j * 8) * CH + c0 + tx];
  __syncthreads();
  #pragma unroll
  for (int j = 0; j < 4; ++j)
    out[((size_t)b * CH + c0 + ty + j * 8) * TLEN + t0 + tx] =
        ls[tx][ty + j * 8] * mask[b * TLEN + t0 + tx];
}

// ---------- generic MFMA GEMM, BK=64, M-tile = MFR*32, reg-prefetch pipelined ----------
// OUTMODE: 0=bf16 [B][T][N], 3=QKV fused epilogue
template<int OUTMODE, int NSHIFT, int RELU, int KSPLIT, int MFR>
__global__ __launch_bounds__(256) void gemm_tc(
    const unsigned short* __restrict__ A, const unsigned short* __restrict__ Bw,
    const float* __restrict__ bias, void* __restrict__ Y, int Cin, int N)
{
  constexpr int HALO = (NSHIFT == 3) ? 1 : 0;
  constexpr int AROWS = MFR * 32 + 2 * HALO;
  constexpr int ACH = (AROWS * 8 + 255) / 256;       // per-thread A-stage chunks
  constexpr int BCH = (NSHIFT * 64 * 8) / 256;       // per-thread B-stage chunks (exact)
  __shared__ __align__(16) unsigned short As[AROWS][72];
  __shared__ __align__(16) unsigned short Bs[NSHIFT][64][72];
  int zz = blockIdx.z;
  int b = zz / KSPLIT, ks = zz % KSPLIT;
  int t0 = blockIdx.x * (MFR * 32), n0 = blockIdx.y * 64;
  int tid = threadIdx.x;
  int w = tid >> 6, lane = tid & 63;
  int wr = w >> 1, wc = w & 1;
  int lr = lane & 15, lg = lane >> 4;
  const unsigned short* Ab = A + (size_t)b * TLEN * Cin;
  int klen = Cin / KSPLIT, k0 = ks * klen;

  // loop-invariant staging indices
  int ar[ACH], ac8[ACH]; bool aok[ACH], ain[ACH];
  #pragma unroll
  for (int j = 0; j < ACH; ++j) {
    int f = tid + j * 256;
    ar[j] = f >> 3; ac8[j] = (f & 7) * 8;
    aok[j] = (f < AROWS * 8);
    int tg = t0 - HALO + ar[j];
    ain[j] = aok[j] && (!HALO || (tg >= 0 && tg < TLEN));
  }
  int brr[BCH], bkk[BCH], bc8[BCH];
  #pragma unroll
  for (int j = 0; j < BCH; ++j) {
    int f = tid + j * 256;
    bkk[j] = f >> 9; brr[j] = (f >> 3) & 63; bc8[j] = (f & 7) * 8;
  }

  u16x8 areg[ACH], breg[BCH];
  f32x4 acc[MFR][2] = {};

  // prologue: load first K-step into registers
  #pragma unroll
  for (int j = 0; j < ACH; ++j) {
    u16x8 v = {};
    if (ain[j]) v = *(const u16x8*)&Ab[(size_t)(t0 - HALO + ar[j]) * Cin + k0 + ac8[j]];
    areg[j] = v;
  }
  #pragma unroll
  for (int j = 0; j < BCH; ++j)
    breg[j] = *(const u16x8*)&Bw[((size_t)bkk[j] * N + n0 + brr[j]) * Cin + k0 + bc8[j]];

  for (int kc = k0; kc < k0 + klen; kc += 64) {
    __syncthreads();     // previous MFMA phase done reading LDS
    #pragma unroll
    for (int j = 0; j < ACH; ++j)
      if (aok[j]) *(u16x8*)&As[ar[j]][ac8[j]] = areg[j];
    #pragma unroll
    for (int j = 0; j < BCH; ++j)
      *(u16x8*)&Bs[bkk[j]][brr[j]][bc8[j]] = breg[j];
    if (kc + 64 < k0 + klen) {   // issue next K-step's loads; latency hides under MFMA
      int kn = kc + 64;
      #pragma unroll
      for (int j = 0; j < ACH; ++j) {
        u16x8 v = {};
        if (ain[j]) v = *(const u16x8*)&Ab[(size_t)(t0 - HALO + ar[j]) * Cin + kn + ac8[j]];
        areg[j] = v;
      }
      #pragma unroll
      for (int j = 0; j < BCH; ++j)
        breg[j] = *(const u16x8*)&Bw[((size_t)bkk[j] * N + n0 + brr[j]) * Cin + kn + bc8[j]];
    }
    __syncthreads();
    #pragma unroll
    for (int kk = 0; kk < NSHIFT; ++kk) {
      #pragma unroll
      for (int k2 = 0; k2 < 2; ++k2) {
        bf16x8 b0 = *(const bf16x8*)&Bs[kk][wc * 32 + lr][k2 * 32 + lg * 8];
        bf16x8 b1 = *(const bf16x8*)&Bs[kk][wc * 32 + 16 + lr][k2 * 32 + lg * 8];
        #pragma unroll
        for (int i = 0; i < MFR; ++i) {
          bf16x8 a = *(const bf16x8*)&As[wr * MFR * 16 + i * 16 + lr + kk][k2 * 32 + lg * 8];
          acc[i][0] = __builtin_amdgcn_mfma_f32_16x16x32_bf16(a, b0, acc[i][0], 0, 0, 0);
          acc[i][1] = __builtin_amdgcn_mfma_f32_16x16x32_bf16(a, b1, acc[i][1], 0, 0, 0);
        }
      }
    }
  }
  #pragma unroll
  for (int i = 0; i < MFR; ++i) {
    #pragma unroll
    for (int j = 0; j < 2; ++j) {
      int n = n0 + wc * 32 + j * 16 + lr;
      float bb = (ks == 0) ? bias[n] : 0.f;
      float vals[4];
      #pragma unroll
      for (int r = 0; r < 4; ++r) {
        float v = acc[i][j][r] + bb;
        if (RELU) v = fmaxf(v, 0.f);
        vals[r] = v;
      }
      int trow = t0 + wr * MFR * 16 + i * 16 + lg * 4;
      if (OUTMODE == 0) {
        unsigned short* Yp = (unsigned short*)Y + ((size_t)b * TLEN + trow) * N + n;
        #pragma unroll
        for (int r = 0; r < 4; ++r) Yp[(size_t)r * N] = f2bf(vals[r]);
      } else {  // QKV fused: n tile uniform within one of Q/K/V
        unsigned short* base = (unsigned short*)Y;
        if (n0 < 192) {
          unsigned short* Yp = base + ((size_t)b * TLEN + trow) * CH + n;
          #pragma unroll
          for (int r = 0; r < 4; ++r) Yp[(size_t)r * CH] = f2bf(vals[r]);
        } else if (n0 < 384) {
          unsigned short* Yp = base + (size_t)NBCT + ((size_t)b * TLEN + trow) * CH + (n - 192);
          #pragma unroll
          for (int r = 0; r < 4; ++r) Yp[(size_t)r * CH] = f2bf(vals[r]);
        } else {
          ushort4 pk;
          pk.x = f2bf(vals[0]); pk.y = f2bf(vals[1]); pk.z = f2bf(vals[2]); pk.w = f2bf(vals[3]);
          *(ushort4*)(base + 2 * (size_t)NBCT + ((size_t)b * CH + (n - 384)) * TLEN + trow) = pk;
        }
      }
    }
  }
}

// ---------- fused flash-combine + WO GEMM + residual + LayerNorm ----------
__global__ __launch_bounds__(256) void gemm_wolnc(
    const unsigned short* __restrict__ Opart, const float* __restrict__ mG,
    const float* __restrict__ lG, const float* __restrict__ bandG,
    const float* __restrict__ relv,
    const unsigned short* __restrict__ Bw, const float* __restrict__ bias,
    const float* __restrict__ g, const float* __restrict__ bt,
    float* __restrict__ Xc, unsigned short* __restrict__ Xbf)
{
  __shared__ __align__(16) unsigned short Af[16][200];  // AO tile, full K=192
  __shared__ __align__(16) unsigned short Bs[192][72];
  __shared__ float sred[4][16][2];
  __shared__ float ce[16][2][4];
  __shared__ float cinvL[16][2];
  __shared__ float cbx[16][2][9];
  __shared__ float relvS[9 * 96];
  int b = blockIdx.y;
  int t0 = blockIdx.x * 16;
  int tid = threadIdx.x;
  int w = tid >> 6, lane = tid & 63;
  int lr = lane & 15, lg = lane >> 4;
  int brr[6], bc8[6];
  #pragma unroll
  for (int j = 0; j < 6; ++j) { int f = tid + j * 256; brr[j] = f >> 3; bc8[j] = (f & 7) * 8; }

  u16x8 breg[6];
  #pragma unroll
  for (int j = 0; j < 6; ++j)
    breg[j] = *(const u16x8*)&Bw[(size_t)brr[j] * CH + bc8[j]];

  for (int f = tid; f < 864; f += 256) relvS[f] = relv[f];
  if (tid < 32) {   // per-(row,head) combine stats
    int r = tid >> 1, h = tid & 1;
    int t = t0 + r;
    size_t grow = (size_t)(b * 2 + h) * TLEN + t;
    float mv[SCH], lv[SCH], m = -1e30f;
    #pragma unroll
    for (int c = 0; c < SCH; ++c) {
      mv[c] = mG[(size_t)c * BHT + grow];
      lv[c] = lG[(size_t)c * BHT + grow];
      m = fmaxf(m, mv[c]);
    }
    float L = 0.f;
    #pragma unroll
    for (int c = 0; c < SCH; ++c) {
      float e = exp2a(mv[c] - m);
      ce[r][h][c] = e; L += lv[c] * e;
    }
    cinvL[r][h] = 1.f / L;
    #pragma unroll
    for (int dd = 0; dd < 9; ++dd) {
      int s = t + dd - WIN;
      cbx[r][h][dd] = (s >= 0 && s < TLEN) ? exp2a(bandG[grow * 9 + dd] - m) : 0.f;
    }
  }
  __syncthreads();
  // build AO tile into Af
  #pragma unroll
  for (int j = 0; j < 12; ++j) {
    int f = tid + j * 256;
    int row = f / 192, col = f - row * 192;
    int h = (col >= 96) ? 1 : 0, d = col - h * 96;
    size_t grow = (size_t)(b * 2 + h) * TLEN + t0 + row;
    float acc = 0.f;
    #pragma unroll
    for (int c = 0; c < SCH; ++c)
      acc += bf2f(Opart[((size_t)c * BHT + grow) * 96 + d]) * ce[row][h][c];
    #pragma unroll
    for (int dd = 0; dd < 9; ++dd)
      acc += cbx[row][h][dd] * relvS[dd * 96 + d];
    Af[row][col] = f2bf(acc * cinvL[row][h]);
  }

  f32x4 acc3[3] = {};
  for (int kc = 0; kc < CH; kc += 64) {
    __syncthreads();   // (first iter: Af/stats visible) prev MFMA done reading Bs
    #pragma unroll
    for (int j = 0; j < 6; ++j) *(u16x8*)&Bs[brr[j]][bc8[j]] = breg[j];
    if (kc + 64 < CH) {
      int kn = kc + 64;
      #pragma unroll
      for (int j = 0; j < 6; ++j)
        breg[j] = *(const u16x8*)&Bw[(size_t)brr[j] * CH + kn + bc8[j]];
    }
    __syncthreads();
    #pragma unroll
    for (int k2 = 0; k2 < 2; ++k2) {
      bf16x8 a = *(const bf16x8*)&Af[lr][kc + k2 * 32 + lg * 8];
      #pragma unroll
      for (int j = 0; j < 3; ++j) {
        bf16x8 bfr = *(const bf16x8*)&Bs[w * 48 + j * 16 + lr][k2 * 32 + lg * 8];
        acc3[j] = __builtin_amdgcn_mfma_f32_16x16x32_bf16(a, bfr, acc3[j], 0, 0, 0);
      }
    }
  }
  // epilogue: bias + residual + per-row LayerNorm
  float vv[3][4], sp[4] = {}, sp2[4] = {};
  #pragma unroll
  for (int j = 0; j < 3; ++j) {
    int col = w * 48 + j * 16 + lr;
    float bb = bias[col];
    #pragma unroll
    for (int r = 0; r < 4; ++r) {
      int row = t0 + lg * 4 + r;
      float y = acc3[j][r] + bb;
      float res = Xc[((size_t)b * TLEN + row) * CH + col];
      float t = res + y;
      vv[j][r] = t; sp[r] += t; sp2[r] += t * t;
    }
  }
  #pragma unroll
  for (int m = 1; m <= 8; m <<= 1)
    #pragma unroll
    for (int r = 0; r < 4; ++r) {
      sp[r] += __shfl_xor(sp[r], m, 64);
      sp2[r] += __shfl_xor(sp2[r], m, 64);
    }
  __syncthreads();
  if (lr == 0) {
    #pragma unroll
    for (int r = 0; r < 4; ++r) {
      sred[w][lg * 4 + r][0] = sp[r];
      sred[w][lg * 4 + r][1] = sp2[r];
    }
  }
  __syncthreads();
  #pragma unroll
  for (int r = 0; r < 4; ++r) {
    int row = lg * 4 + r;
    float s  = sred[0][row][0] + sred[1][row][0] + sred[2][row][0] + sred[3][row][0];
    float s2 = sred[0][row][1] + sred[1][row][1] + sred[2][row][1] + sred[3][row][1];
    float mean = s * (1.f / CH);
    float var = s2 * (1.f / CH) - mean * mean;
    float rs = rsqrtf(var + EPSV);
    #pragma unroll
    for (int j = 0; j < 3; ++j) {
      int col = w * 48 + j * 16 + lr;
      float o = g[col] * (vv[j][r] - mean) * rs + bt[col];
      size_t idx = ((size_t)b * TLEN + t0 + row) * CH + col;
      Xc[idx] = o; Xbf[idx] = f2bf(o);
    }
  }
}

// ---------- fused FFN2 (conv-3) + residual + LayerNorm: 32 rows x full 192 cols ----------
// y[t][o] = sum_kk sum_c W2[kk][o][c] * H[t+kk-1][c]; then LN(res + y + bias).
__global__ __launch_bounds__(256) void gemm_f2lnc(
    const unsigned short* __restrict__ A, const unsigned short* __restrict__ Bw,
    const float* __restrict__ bias, const float* __restrict__ g,
    const float* __restrict__ bt, float* __restrict__ Xc, unsigned short* __restrict__ Xbf)
{
  __shared__ __align__(16) unsigned short As[34][72];
  __shared__ __align__(16) unsigned short Bs[192][72];
  __shared__ float sred[4][32][2];
  int b = blockIdx.y;
  int t0 = blockIdx.x * 32;
  int tid = threadIdx.x;
  int w = tid >> 6, lane = tid & 63;
  int lr = lane & 15, lg = lane >> 4;
  const unsigned short* Ab = A + (size_t)b * TLEN * FCH;
  // A stage: 34 rows x 8 chunks = 272
  int ar[2], ac8[2]; bool aok[2], ain[2];
  #pragma unroll
  for (int j = 0; j < 2; ++j) {
    int f = tid + j * 256;
    ar[j] = f >> 3; ac8[j] = (f & 7) * 8;
    aok[j] = f < 272;
    int tg = t0 - 1 + ar[j];
    ain[j] = aok[j] && tg >= 0 && tg < TLEN;
  }
  // B stage: 192 rows x 8 chunks = 1536 = 6/thread exact
  int brr[6], bc8[6];
  #pragma unroll
  for (int j = 0; j < 6; ++j) { int f = tid + j * 256; brr[j] = f >> 3; bc8[j] = (f & 7) * 8; }

  u16x8 areg[2], breg[6];
  f32x4 acc[2][3] = {};
  #pragma unroll
  for (int j = 0; j < 2; ++j) {
    u16x8 v = {};
    if (ain[j]) v = *(const u16x8*)&Ab[(size_t)(t0 - 1 + ar[j]) * FCH + ac8[j]];
    areg[j] = v;
  }
  #pragma unroll
  for (int j = 0; j < 6; ++j)
    breg[j] = *(const u16x8*)&Bw[(size_t)brr[j] * FCH + bc8[j]];   // kk=0, kc=0

  for (int kc = 0; kc < FCH; kc += 64) {
    for (int kk = 0; kk < 3; ++kk) {
      __syncthreads();
      if (kk == 0) {
        #pragma unroll
        for (int j = 0; j < 2; ++j)
          if (aok[j]) *(u16x8*)&As[ar[j]][ac8[j]] = areg[j];
      }
      #pragma unroll
      for (int j = 0; j < 6; ++j) *(u16x8*)&Bs[brr[j]][bc8[j]] = breg[j];
      bool last = (kk == 2) && (kc + 64 >= FCH);
      if (!last) {
        int nkk = (kk == 2) ? 0 : kk + 1;
        int nkc = (kk == 2) ? kc + 64 : kc;
        #pragma unroll
        for (int j = 0; j < 6; ++j)
          breg[j] = *(const u16x8*)&Bw[((size_t)nkk * CH + brr[j]) * FCH + nkc + bc8[j]];
        if (kk == 2) {
          #pragma unroll
          for (int j = 0; j < 2; ++j) {
            u16x8 v = {};
            if (ain[j]) v = *(const u16x8*)&Ab[(size_t)(t0 - 1 + ar[j]) * FCH + nkc + ac8[j]];
            areg[j] = v;
          }
        }
      }
      __syncthreads();
      #pragma unroll
      for (int k2 = 0; k2 < 2; ++k2) {
        #pragma unroll
        for (int rf = 0; rf < 2; ++rf) {
          bf16x8 a = *(const bf16x8*)&As[rf * 16 + lr + kk][k2 * 32 + lg * 8];
          #pragma unroll
          for (int j = 0; j < 3; ++j) {
            bf16x8 bfr = *(const bf16x8*)&Bs[w * 48 + j * 16 + lr][k2 * 32 + lg * 8];
            acc[rf][j] = __builtin_amdgcn_mfma_f32_16x16x32_bf16(a, bfr, acc[rf][j], 0, 0, 0);
          }
        }
      }
    }
  }
  // epilogue: bias + residual + per-row LayerNorm (32 rows)
  float vv[2][3][4], sp[2][4] = {}, sp2[2][4] = {};
  #pragma unroll
  for (int rf = 0; rf < 2; ++rf)
    #pragma unroll
    for (int j = 0; j < 3; ++j) {
      int col = w * 48 + j * 16 + lr;
      float bb = bias[col];
      #pragma unroll
      for (int r = 0; r < 4; ++r) {
        int row = t0 + rf * 16 + lg * 4 + r;
        float y = acc[rf][j][r] + bb;
        float res = Xc[((size_t)b * TLEN + row) * CH + col];
        float t = res + y;
        vv[rf][j][r] = t; sp[rf][r] += t; sp2[rf][r] += t * t;
      }
    }
  #pragma unroll
  for (int m = 1; m <= 8; m <<= 1)
    #pragma unroll
    for (int rf = 0; rf < 2; ++rf)
      #pragma unroll
      for (int r = 0; r < 4; ++r) {
        sp[rf][r] += __shfl_xor(sp[rf][r], m, 64);
        sp2[rf][r] += __shfl_xor(sp2[rf][r], m, 64);
      }
  __syncthreads();
  if (lr == 0) {
    #pragma unroll
    for (int rf = 0; rf < 2; ++rf)
      #pragma unroll
      for (int r = 0; r < 4; ++r) {
        sred[w][rf * 16 + lg * 4 + r][0] = sp[rf][r];
        sred[w][rf * 16 + lg * 4 + r][1] = sp2[rf][r];
      }
  }
  __syncthreads();
  #pragma unroll
  for (int rf = 0; rf < 2; ++rf)
    #pragma unroll
    for (int r = 0; r < 4; ++r) {
      int row = rf * 16 + lg * 4 + r;
      float s  = sred[0][row][0] + sred[1][row][0] + sred[2][row][0] + sred[3][row][0];
      float s2 = sred[0][row][1] + sred[1][row][1] + sred[2][row][1] + sred[3][row][1];
      float mean = s * (1.f / CH);
      float var = s2 * (1.f / CH) - mean * mean;
      float rs = rsqrtf(var + EPSV);
      #pragma unroll
      for (int j = 0; j < 3; ++j) {
        int col = w * 48 + j * 16 + lr;
        float o = g[col] * (vv[rf][j][r] - mean) * rs + bt[col];
        size_t idx = ((size_t)b * TLEN + t0 + row) * CH + col;
        Xc[idx] = o; Xbf[idx] = f2bf(o);
      }
    }
}

// ---------- flash attention partial (s-chunked, swapped-QK, base-2, dbuf, XCD-pinned) ----------
__global__ __launch_bounds__(256, 4) void flash_part(
    const unsigned short* __restrict__ Qg, const unsigned short* __restrict__ Kg,
    const unsigned short* __restrict__ Vg, const float* __restrict__ relk,
    unsigned short* __restrict__ Opart, float* __restrict__ mG, float* __restrict__ lG,
    float* __restrict__ bandG)
{
  __shared__ __align__(16) unsigned short KsB[64 * 104];
  __shared__ __align__(16) unsigned short QV[96 * 72];   // Qs[64][104] then Vs[96][72]
  __shared__ float qrk[64][9];
  int id = blockIdx.x;
  int bh = id & 7;                     // XCD-pinned
  int rest = id >> 3;
  int t0 = (rest & 31) * 64;
  int zc = rest >> 5;                  // chunk index 0..SCH-1
  int c0 = zc * CHUNK;
  int b = bh >> 1, h = bh & 1;
  int tid = threadIdx.x; int w = tid >> 6, lane = tid & 63;
  int lr = lane & 15, lg = lane >> 4;
  int q = w * 16 + lr;                 // this thread's softmax-state query row
  const unsigned short* Qb = Qg + (size_t)b * TLEN * CH + h * DKH;
  const unsigned short* Kb = Kg + (size_t)b * TLEN * CH + h * DKH;
  const unsigned short* Vb = Vg + ((size_t)b * CH + h * DKH) * TLEN;
  unsigned short (*Qs)[104] = (unsigned short(*)[104])QV;
  unsigned short (*Vs)[72] = (unsigned short(*)[72])QV;
  unsigned short (*Ks)[104] = (unsigned short(*)[104])KsB;
  unsigned short (*Ps)[72] = (unsigned short(*)[72])KsB;   // alias: valid after barrier C

  // staging index precompute (3 u16x8 per thread for K and for V)
  int kr[3], kc8[3], vr[3], vc8[3];
  #pragma unroll
  for (int j = 0; j < 3; ++j) {
    int f = tid + j * 256;
    kr[j] = f / 12; kc8[j] = (f % 12) * 8;
    vr[j] = f >> 3; vc8[j] = (f & 7) * 8;
  }

  for (int f = tid; f < 64 * 12; f += 256) {
    int r = f / 12, c8 = (f % 12) * 8;
    *(u16x8*)&Qs[r][c8] = *(const u16x8*)&Qb[(size_t)(t0 + r) * CH + c8];
  }
  __syncthreads();
  bool overlap = (t0 + 64 + WIN > c0) && (t0 - WIN < c0 + CHUNK);
  if (overlap) {
    for (int f = tid; f < 576; f += 256) {
      int r = f / 9, dd = f - (f / 9) * 9;
      float s = 0.f;
      #pragma unroll 8
      for (int d = 0; d < DKH; ++d) s += bf2f(Qs[r][d]) * relk[dd * DKH + d];
      qrk[r][dd] = s;    // already in base-2 domain (Q pre-scaled by log2e)
    }
  }
  bf16x8 qf[3];
  #pragma unroll
  for (int kc = 0; kc < 3; ++kc) qf[kc] = *(const bf16x8*)&Qs[q][kc * 32 + lg * 8];
  float mrow = -1e30f, lrow = 0.f;   // lrow: per-thread partial (16 cols); reduced at epilogue
  f32x4 oacc[6] = {};

  // prologue: prefetch tile 0 into registers
  u16x8 kreg[3], vreg[3];
  #pragma unroll
  for (int j = 0; j < 3; ++j)
    kreg[j] = *(const u16x8*)&Kb[(size_t)(c0 + kr[j]) * CH + kc8[j]];
  #pragma unroll
  for (int j = 0; j < 3; ++j)
    vreg[j] = *(const u16x8*)&Vb[(size_t)vr[j] * TLEN + c0 + vc8[j]];

  for (int it = 0; it < CHUNK / 64; ++it) {
    int s0 = c0 + it * 64;
    __syncthreads();                      // A: prev PV done reading Ps(=KsB) and Vs
    #pragma unroll
    for (int j = 0; j < 3; ++j) *(u16x8*)&Ks[kr[j]][kc8[j]] = kreg[j];
    #pragma unroll
    for (int j = 0; j < 3; ++j) *(u16x8*)&Vs[vr[j]][vc8[j]] = vreg[j];
    if (it + 1 < CHUNK / 64) {            // issue next tile's loads (hide under compute)
      int sn = s0 + 64;
      #pragma unroll
      for (int j = 0; j < 3; ++j)
        kreg[j] = *(const u16x8*)&Kb[(size_t)(sn + kr[j]) * CH + kc8[j]];
      #pragma unroll
      for (int j = 0; j < 3; ++j)
        vreg[j] = *(const u16x8*)&Vb[(size_t)vr[j] * TLEN + sn + vc8[j]];
    }
    __syncthreads();                      // B: Ks/Vs ready

    // S^T tile: sacc[ct][r] = S[s = ct*16+lg*4+r][q]
    f32x4 sacc[4] = {};
    __builtin_amdgcn_s_setprio(1);
    #pragma unroll
    for (int kc = 0; kc < 3; ++kc) {
      #pragma unroll
      for (int ct = 0; ct < 4; ++ct) {
        bf16x8 kfr = *(const bf16x8*)&Ks[ct * 16 + lr][kc * 32 + lg * 8];
        sacc[ct] = __builtin_amdgcn_mfma_f32_16x16x32_bf16(kfr, qf[kc], sacc[ct], 0, 0, 0);
      }
    }
    __builtin_amdgcn_s_setprio(0);
    // band bias (only on diagonal-overlapping tiles; block-uniform predicate)
    if (s0 + 64 + WIN > t0 && s0 < t0 + 64 + WIN) {
      #pragma unroll
      for (int ct = 0; ct < 4; ++ct)
        #pragma unroll
        for (int r = 0; r < 4; ++r) {
          int dlt = (s0 + ct * 16 + lg * 4 + r) - (t0 + q);
          if (dlt >= -WIN && dlt <= WIN) {
            float v = sacc[ct][r] + qrk[q][dlt + WIN];
            sacc[ct][r] = v;
            bandG[((size_t)bh * TLEN + t0 + q) * 9 + dlt + WIN] = v;  // logit, exactly-once
          }
        }
    }
    float cm[4];
    #pragma unroll
    for (int ct = 0; ct < 4; ++ct)
      cm[ct] = fmaxf(fmaxf(sacc[ct][0], sacc[ct][1]), fmaxf(sacc[ct][2], sacc[ct][3]));
    float tmax = fmaxf(fmaxf(cm[0], cm[1]), fmaxf(cm[2], cm[3]));
    tmax = fmaxf(tmax, __shfl_xor(tmax, 16, 64));
    tmax = fmaxf(tmax, __shfl_xor(tmax, 32, 64));
    // defer-rescale: skip alpha path if no q in this wave grew past mrow+8
    bool upd = !__all(tmax <= mrow + 8.f);
    float mnew = upd ? fmaxf(mrow, tmax) : mrow;
    float psum = 0.f;
    ushort4 pk[4];
    #pragma unroll
    for (int ct = 0; ct < 4; ++ct) {
      float p0 = exp2a(sacc[ct][0] - mnew), p1 = exp2a(sacc[ct][1] - mnew);
      float p2 = exp2a(sacc[ct][2] - mnew), p3 = exp2a(sacc[ct][3] - mnew);
      psum += (p0 + p1) + (p2 + p3);
      pk[ct].x = f2bf(p0); pk[ct].y = f2bf(p1); pk[ct].z = f2bf(p2); pk[ct].w = f2bf(p3);
    }
    if (upd) {
      float alpha = exp2a(mrow - mnew);      // alpha for q = w*16+lr
      lrow *= alpha;
      // oacc rows are q_out = w*16 + lg*4 + r -> need THOSE rows' alphas
      float alo[4];
      #pragma unroll
      for (int r = 0; r < 4; ++r) alo[r] = __shfl(alpha, lg * 4 + r, 64);
      #pragma unroll
      for (int dt = 0; dt < 6; ++dt)
        #pragma unroll
        for (int r = 0; r < 4; ++r) oacc[dt][r] *= alo[r];
      mrow = mnew;
    }
    lrow += psum;
    __syncthreads();                      // C: all QK^T reads of Ks done -> Ps may overwrite
    #pragma unroll
    for (int ct = 0; ct < 4; ++ct)
      *(ushort4*)&Ps[q][ct * 16 + lg * 4] = pk[ct];
    __builtin_amdgcn_s_setprio(1);
    #pragma unroll
    for (int ks = 0; ks < 2; ++ks) {
      bf16x8 pa = *(const bf16x8*)&Ps[q][ks * 32 + lg * 8];   // same-wave rows: no barrier
      #pragma unroll
      for (int dt = 0; dt < 6; ++dt) {
        bf16x8 vf = *(const bf16x8*)&Vs[dt * 16 + lr][ks * 32 + lg * 8];
        oacc[dt] = __builtin_amdgcn_mfma_f32_16x16x32_bf16(pa, vf, oacc[dt], 0, 0, 0);
      }
    }
    __builtin_amdgcn_s_setprio(0);
  }

  size_t pbase = ((size_t)zc * (BATCH * NH) + bh) * TLEN + t0;
  #pragma unroll
  for (int dt = 0; dt < 6; ++dt)
    #pragma unroll
    for (int r = 0; r < 4; ++r)
      Opart[(pbase + w * 16 + lg * 4 + r) * 96 + dt * 16 + lr] = f2bf(oacc[dt][r]);
  // reduce the deferred per-thread partial l across the 4 lanes sharing q
  float lfull = lrow;
  lfull += __shfl_xor(lfull, 16, 64);
  lfull += __shfl_xor(lfull, 32, 64);
  if (lg == 0) {
    mG[pbase + q] = mrow;
    lG[pbase + q] = lfull;
  }
}

extern "C" void kernel_launch(void* const* d_in, const int* in_sizes, int n_in,
                              void* d_out, int out_size, void* d_ws, size_t ws_size,
                              hipStream_t stream) {
  (void)in_sizes; (void)n_in; (void)out_size; (void)ws_size;
  const float* x    = (const float*)d_in[0];
  const float* mask = (const float*)d_in[1];
  const float* wq   = (const float*)d_in[2];
  const float* bq   = (const float*)d_in[3];
  const float* wk   = (const float*)d_in[4];
  const float* bk   = (const float*)d_in[5];
  const float* wv   = (const float*)d_in[6];
  const float* bv   = (const float*)d_in[7];
  const float* wo   = (const float*)d_in[8];
  const float* bo   = (const float*)d_in[9];
  const float* relk = (const float*)d_in[10];
  const float* relv = (const float*)d_in[11];
  const float* ln1g = (const float*)d_in[12];
  const float* ln1b = (const float*)d_in[13];
  const float* fw1  = (const float*)d_in[14];
  const float* fb1  = (const float*)d_in[15];
  const float* fw2  = (const float*)d_in[16];
  const float* fb2  = (const float*)d_in[17];
  const float* ln2g = (const float*)d_in[18];
  const float* ln2b = (const float*)d_in[19];

  char* p = (char*)d_ws;
  float* Xc = (float*)p;                      p += (size_t)NBCT * 4;
  unsigned short* Xbf  = (unsigned short*)p;  p += (size_t)NBCT * 2;
  unsigned short* Qbf  = (unsigned short*)p;  p += (size_t)NBCT * 2;  // K,V contiguous after Q
  unsigned short* Kbf  = (unsigned short*)p;  p += (size_t)NBCT * 2;
  unsigned short* Vbf  = (unsigned short*)p;  p += (size_t)NBCT * 2;
  char* R = p;                                p += (size_t)NBCT * 16;
  unsigned short* Opart = (unsigned short*)R;              // bf16 partials: SCH*BHT*96*2 = NBCT*8 bytes
  unsigned short* Hbf = (unsigned short*)(R + (size_t)NBCT * 2);  // overlays dead Opart region safely
  float* mG = (float*)p;                      p += (size_t)SCH * BHT * 4;
  float* lG = (float*)p;                      p += (size_t)SCH * BHT * 4;
  float* bandG = (float*)p;                   p += (size_t)BHT * 9 * 4;
  unsigned short* Wqkv = (unsigned short*)p;  p += (size_t)LNUM * 576 * CH * 2;
  float* Bqkv = (float*)p;                    p += (size_t)LNUM * 576 * 4;
  unsigned short* Wob  = (unsigned short*)p;  p += (size_t)LNUM * CH * CH * 2;
  unsigned short* W1b  = (unsigned short*)p;  p += (size_t)LNUM * 3 * FCH * CH * 2;
  unsigned short* W2b  = (unsigned short*)p;

  prep_all<<<2048, 256, 0, stream>>>(wq, wk, wv, bq, bk, bv, wo, fw1, fw2,
                                     Wqkv, Bqkv, Wob, W1b, W2b);
  tin_kernel<<<dim3(TLEN / 32, CH / 32, BATCH), 256, 0, stream>>>(x, mask, Xc, Xbf);

  for (int l = 0; l < LNUM; ++l) {
    gemm_tc<3, 1, 0, 1, 2><<<dim3(32, 9, 4), 256, 0, stream>>>(
        Xbf, Wqkv + (size_t)l * 576 * CH, Bqkv + l * 576, Qbf, CH, 576);
    flash_part<<<dim3(32 * 8 * SCH), 256, 0, stream>>>(
        Qbf, Kbf, Vbf, relk + (size_t)l * 9 * DKH, Opart, mG, lG, bandG);
    gemm_wolnc<<<dim3(TLEN / 16, BATCH), 256, 0, stream>>>(
        Opart, mG, lG, bandG, relv + (size_t)l * 9 * DKH,
        Wob + (size_t)l * CH * CH, bo + l * CH,
        ln1g + l * CH, ln1b + l * CH, Xc, Xbf);
    gemm_tc<0, 3, 1, 1, 2><<<dim3(32, 12, 4), 256, 0, stream>>>(
        Xbf, W1b + (size_t)l * 3 * FCH * CH, fb1 + l * FCH, Hbf, CH, FCH);
    // FFN2 + residual + LN2 fused (32 rows x full 192 cols)
    gemm_f2lnc<<<dim3(TLEN / 32, BATCH), 256, 0, stream>>>(
        Hbf, W2b + (size_t)l * 3 * CH * FCH, fb2 + l * CH,
        ln2g + l * CH, ln2b + l * CH, Xc, Xbf);
  }
  tout_kernel<<<dim3(TLEN / 32, CH / 32, BATCH), 256, 0, stream>>>(Xc, mask, (float*)d_out);
}

// Round 19
// 585.256 us; speedup vs baseline: 1.0203x; 1.0203x over previous
//
#include <hip/hip_runtime.h>

#define LNUM 6
#define CH 192
#define FCH 768
#define NH 2
#define DKH 96
#define WIN 4
#define BATCH 4
#define TLEN 2048
#define EPSV 1e-5f
#define SCH 4
#define CHUNK (TLEN / SCH)
#define NBCT (BATCH*CH*TLEN)
#define NBFT (BATCH*FCH*TLEN)
#define BHT (BATCH*NH*TLEN)    // 16384

typedef __attribute__((ext_vector_type(8))) short bf16x8;
typedef __attribute__((ext_vector_type(4))) float f32x4;
typedef __attribute__((ext_vector_type(8))) unsigned short u16x8;

__device__ __forceinline__ unsigned short f2bf(float f) {
  unsigned int u = __builtin_bit_cast(unsigned int, f);
  u = (u + 0x7fffu + ((u >> 16) & 1u)) >> 16;
  return (unsigned short)u;
}
__device__ __forceinline__ float bf2f(unsigned short s) {
  return __builtin_bit_cast(float, ((unsigned int)s) << 16);
}
__device__ __forceinline__ float exp2a(float x) {   // hardware 2^x, hazard-safe
#if __has_builtin(__builtin_amdgcn_exp2f)
  return __builtin_amdgcn_exp2f(x);
#else
  return exp2f(x);
#endif
}

// ---------- fused weight prep (QKV fuse+scale, WO cvt, FFN w1/w2 transpose) ----------
__global__ __launch_bounds__(256) void prep_all(
    const float* __restrict__ wq, const float* __restrict__ wk, const float* __restrict__ wv,
    const float* __restrict__ bq, const float* __restrict__ bk, const float* __restrict__ bv,
    const float* __restrict__ wo, const float* __restrict__ fw1, const float* __restrict__ fw2,
    unsigned short* __restrict__ Wqkv, float* __restrict__ Bqkv,
    unsigned short* __restrict__ Wob, unsigned short* __restrict__ W1b,
    unsigned short* __restrict__ W2b)
{
  const float qscale = 0.10206207261596575f * 1.4426950408889634f;  // dk^-0.5 * log2(e)
  const int n0 = LNUM * 576 * CH;            // qkv
  const int n1 = LNUM * CH * CH;             // wo
  const int n2 = LNUM * 3 * FCH * CH;        // w1
  const int n3 = LNUM * 3 * CH * FCH;        // w2
  int total = n0 + n1 + n2 + n3;
  for (int i = blockIdx.x * 256 + threadIdx.x; i < total; i += gridDim.x * 256) {
    if (i < n0) {
      int c = i % CH; int n = (i / CH) % 576; int l = i / (CH * 576);
      float sc = (n < 192) ? qscale : 1.f;
      const float* src = (n < 192) ? wq : (n < 384) ? wk : wv;
      int nn = n % 192;
      Wqkv[i] = f2bf(src[((size_t)l * CH + nn) * CH + c] * sc);
      if (c == 0) {
        const float* bs = (n < 192) ? bq : (n < 384) ? bk : bv;
        Bqkv[l * 576 + n] = bs[l * CH + nn] * sc;
      }
    } else if (i < n0 + n1) {
      int j = i - n0;
      Wob[j] = f2bf(wo[j]);
    } else if (i < n0 + n1 + n2) {
      int j = i - n0 - n1;           // dst [L][3][FCH][CH]
      int c = j % CH; int t1 = j / CH;
      int f = t1 % FCH; int t2 = t1 / FCH;
      int kk = t2 % 3; int l = t2 / 3;
      W1b[j] = f2bf(fw1[(((size_t)l * FCH + f) * CH + c) * 3 + kk]);
    } else {
      int j = i - n0 - n1 - n2;      // dst [L][3][CH][FCH]
      int c = j % FCH; int t1 = j / FCH;
      int f = t1 % CH; int t2 = t1 / CH;
      int kk = t2 % 3; int l = t2 / 3;
      W2b[j] = f2bf(fw2[(((size_t)l * CH + f) * FCH + c) * 3 + kk]);
    }
  }
}

// ---------- transpose in/out ----------
__global__ __launch_bounds__(256) void tin_kernel(const float* __restrict__ x,
    const float* __restrict__ mask, float* __restrict__ Xc, unsigned short* __restrict__ Xbf) {
  __shared__ float ls[32][33];
  int b = blockIdx.z; int c0 = blockIdx.y * 32, t0 = blockIdx.x * 32;
  int tx = threadIdx.x & 31, ty = threadIdx.x >> 5;
  #pragma unroll
  for (int j = 0; j < 4; ++j)
    ls[ty + j * 8][tx] = x[((size_t)b * CH + c0 + ty + j * 8) * TLEN + t0 + tx];
  __syncthreads();
  #pragma unroll
  for (int j = 0; j < 4; ++j) {
    int t = t0 + ty + j * 8;
    float v = ls[tx][ty + j * 8] * mask[b * TLEN + t];
    size_t o = ((size_t)b * TLEN + t) * CH + c0 + tx;
    Xc[o] = v; Xbf[o] = f2bf(v);
  }
}

__global__ __launch_bounds__(256) void tout_kernel(const float* __restrict__ Xc,
    const float* __restrict__ mask, float* __restrict__ out) {
  __shared__ float ls[32][33];
  int b = blockIdx.z; int c0 = blockIdx.y * 32, t0 = blockIdx.x * 32;
  int tx = threadIdx.x & 31, ty = threadIdx.x >> 5;
  #pragma unroll
  for (int j = 0; j < 4; ++j)
    ls[ty + j * 8][tx] = Xc[((size_t)b * TLEN + t0 + ty + j * 8) * CH + c0 + tx];
  __syncthreads();
  #pragma unroll
  for (int j = 0; j < 4; ++j)
    out[((size_t)b * CH + c0 + ty + j * 8) * TLEN + t0 + tx] =
        ls[tx][ty + j * 8] * mask[b * TLEN + t0 + tx];
}

// ---------- generic MFMA GEMM, BK=64, M-tile = MFR*32, reg-prefetch pipelined ----------
// OUTMODE: 0=bf16 [B][T][N], 3=QKV fused epilogue
template<int OUTMODE, int NSHIFT, int RELU, int KSPLIT, int MFR>
__global__ __launch_bounds__(256) void gemm_tc(
    const unsigned short* __restrict__ A, const unsigned short* __restrict__ Bw,
    const float* __restrict__ bias, void* __restrict__ Y, int Cin, int N)
{
  constexpr int HALO = (NSHIFT == 3) ? 1 : 0;
  constexpr int AROWS = MFR * 32 + 2 * HALO;
  constexpr int ACH = (AROWS * 8 + 255) / 256;       // per-thread A-stage chunks
  constexpr int BCH = (NSHIFT * 64 * 8) / 256;       // per-thread B-stage chunks (exact)
  __shared__ __align__(16) unsigned short As[AROWS][72];
  __shared__ __align__(16) unsigned short Bs[NSHIFT][64][72];
  int zz = blockIdx.z;
  int b = zz / KSPLIT, ks = zz % KSPLIT;
  int t0 = blockIdx.x * (MFR * 32), n0 = blockIdx.y * 64;
  int tid = threadIdx.x;
  int w = tid >> 6, lane = tid & 63;
  int wr = w >> 1, wc = w & 1;
  int lr = lane & 15, lg = lane >> 4;
  const unsigned short* Ab = A + (size_t)b * TLEN * Cin;
  int klen = Cin / KSPLIT, k0 = ks * klen;

  // loop-invariant staging indices
  int ar[ACH], ac8[ACH]; bool aok[ACH], ain[ACH];
  #pragma unroll
  for (int j = 0; j < ACH; ++j) {
    int f = tid + j * 256;
    ar[j] = f >> 3; ac8[j] = (f & 7) * 8;
    aok[j] = (f < AROWS * 8);
    int tg = t0 - HALO + ar[j];
    ain[j] = aok[j] && (!HALO || (tg >= 0 && tg < TLEN));
  }
  int brr[BCH], bkk[BCH], bc8[BCH];
  #pragma unroll
  for (int j = 0; j < BCH; ++j) {
    int f = tid + j * 256;
    bkk[j] = f >> 9; brr[j] = (f >> 3) & 63; bc8[j] = (f & 7) * 8;
  }

  u16x8 areg[ACH], breg[BCH];
  f32x4 acc[MFR][2] = {};

  // prologue: load first K-step into registers
  #pragma unroll
  for (int j = 0; j < ACH; ++j) {
    u16x8 v = {};
    if (ain[j]) v = *(const u16x8*)&Ab[(size_t)(t0 - HALO + ar[j]) * Cin + k0 + ac8[j]];
    areg[j] = v;
  }
  #pragma unroll
  for (int j = 0; j < BCH; ++j)
    breg[j] = *(const u16x8*)&Bw[((size_t)bkk[j] * N + n0 + brr[j]) * Cin + k0 + bc8[j]];

  for (int kc = k0; kc < k0 + klen; kc += 64) {
    __syncthreads();     // previous MFMA phase done reading LDS
    #pragma unroll
    for (int j = 0; j < ACH; ++j)
      if (aok[j]) *(u16x8*)&As[ar[j]][ac8[j]] = areg[j];
    #pragma unroll
    for (int j = 0; j < BCH; ++j)
      *(u16x8*)&Bs[bkk[j]][brr[j]][bc8[j]] = breg[j];
    if (kc + 64 < k0 + klen) {   // issue next K-step's loads; latency hides under MFMA
      int kn = kc + 64;
      #pragma unroll
      for (int j = 0; j < ACH; ++j) {
        u16x8 v = {};
        if (ain[j]) v = *(const u16x8*)&Ab[(size_t)(t0 - HALO + ar[j]) * Cin + kn + ac8[j]];
        areg[j] = v;
      }
      #pragma unroll
      for (int j = 0; j < BCH; ++j)
        breg[j] = *(const u16x8*)&Bw[((size_t)bkk[j] * N + n0 + brr[j]) * Cin + kn + bc8[j]];
    }
    __syncthreads();
    #pragma unroll
    for (int kk = 0; kk < NSHIFT; ++kk) {
      #pragma unroll
      for (int k2 = 0; k2 < 2; ++k2) {
        bf16x8 b0 = *(const bf16x8*)&Bs[kk][wc * 32 + lr][k2 * 32 + lg * 8];
        bf16x8 b1 = *(const bf16x8*)&Bs[kk][wc * 32 + 16 + lr][k2 * 32 + lg * 8];
        #pragma unroll
        for (int i = 0; i < MFR; ++i) {
          bf16x8 a = *(const bf16x8*)&As[wr * MFR * 16 + i * 16 + lr + kk][k2 * 32 + lg * 8];
          acc[i][0] = __builtin_amdgcn_mfma_f32_16x16x32_bf16(a, b0, acc[i][0], 0, 0, 0);
          acc[i][1] = __builtin_amdgcn_mfma_f32_16x16x32_bf16(a, b1, acc[i][1], 0, 0, 0);
        }
      }
    }
  }
  #pragma unroll
  for (int i = 0; i < MFR; ++i) {
    #pragma unroll
    for (int j = 0; j < 2; ++j) {
      int n = n0 + wc * 32 + j * 16 + lr;
      float bb = (ks == 0) ? bias[n] : 0.f;
      float vals[4];
      #pragma unroll
      for (int r = 0; r < 4; ++r) {
        float v = acc[i][j][r] + bb;
        if (RELU) v = fmaxf(v, 0.f);
        vals[r] = v;
      }
      int trow = t0 + wr * MFR * 16 + i * 16 + lg * 4;
      if (OUTMODE == 0) {
        unsigned short* Yp = (unsigned short*)Y + ((size_t)b * TLEN + trow) * N + n;
        #pragma unroll
        for (int r = 0; r < 4; ++r) Yp[(size_t)r * N] = f2bf(vals[r]);
      } else {  // QKV fused: n tile uniform within one of Q/K/V
        unsigned short* base = (unsigned short*)Y;
        if (n0 < 192) {
          unsigned short* Yp = base + ((size_t)b * TLEN + trow) * CH + n;
          #pragma unroll
          for (int r = 0; r < 4; ++r) Yp[(size_t)r * CH] = f2bf(vals[r]);
        } else if (n0 < 384) {
          unsigned short* Yp = base + (size_t)NBCT + ((size_t)b * TLEN + trow) * CH + (n - 192);
          #pragma unroll
          for (int r = 0; r < 4; ++r) Yp[(size_t)r * CH] = f2bf(vals[r]);
        } else {
          ushort4 pk;
          pk.x = f2bf(vals[0]); pk.y = f2bf(vals[1]); pk.z = f2bf(vals[2]); pk.w = f2bf(vals[3]);
          *(ushort4*)(base + 2 * (size_t)NBCT + ((size_t)b * CH + (n - 384)) * TLEN + trow) = pk;
        }
      }
    }
  }
}

// ---------- fused flash-combine + WO GEMM + residual + LayerNorm ----------
__global__ __launch_bounds__(256) void gemm_wolnc(
    const unsigned short* __restrict__ Opart, const float* __restrict__ mG,
    const float* __restrict__ lG, const float* __restrict__ bandG,
    const float* __restrict__ relv,
    const unsigned short* __restrict__ Bw, const float* __restrict__ bias,
    const float* __restrict__ g, const float* __restrict__ bt,
    float* __restrict__ Xc, unsigned short* __restrict__ Xbf)
{
  __shared__ __align__(16) unsigned short Af[16][200];  // AO tile, full K=192
  __shared__ __align__(16) unsigned short Bs[192][72];
  __shared__ float sred[4][16][2];
  __shared__ float ce[16][2][4];
  __shared__ float cinvL[16][2];
  __shared__ float cbx[16][2][9];
  __shared__ float relvS[9 * 96];
  int b = blockIdx.y;
  int t0 = blockIdx.x * 16;
  int tid = threadIdx.x;
  int w = tid >> 6, lane = tid & 63;
  int lr = lane & 15, lg = lane >> 4;
  int brr[6], bc8[6];
  #pragma unroll
  for (int j = 0; j < 6; ++j) { int f = tid + j * 256; brr[j] = f >> 3; bc8[j] = (f & 7) * 8; }

  u16x8 breg[6];
  #pragma unroll
  for (int j = 0; j < 6; ++j)
    breg[j] = *(const u16x8*)&Bw[(size_t)brr[j] * CH + bc8[j]];

  for (int f = tid; f < 864; f += 256) relvS[f] = relv[f];
  if (tid < 32) {   // per-(row,head) combine stats
    int r = tid >> 1, h = tid & 1;
    int t = t0 + r;
    size_t grow = (size_t)(b * 2 + h) * TLEN + t;
    float mv[SCH], lv[SCH], m = -1e30f;
    #pragma unroll
    for (int c = 0; c < SCH; ++c) {
      mv[c] = mG[(size_t)c * BHT + grow];
      lv[c] = lG[(size_t)c * BHT + grow];
      m = fmaxf(m, mv[c]);
    }
    float L = 0.f;
    #pragma unroll
    for (int c = 0; c < SCH; ++c) {
      float e = exp2a(mv[c] - m);
      ce[r][h][c] = e; L += lv[c] * e;
    }
    cinvL[r][h] = 1.f / L;
    #pragma unroll
    for (int dd = 0; dd < 9; ++dd) {
      int s = t + dd - WIN;
      cbx[r][h][dd] = (s >= 0 && s < TLEN) ? exp2a(bandG[grow * 9 + dd] - m) : 0.f;
    }
  }
  __syncthreads();
  // build AO tile into Af
  #pragma unroll
  for (int j = 0; j < 12; ++j) {
    int f = tid + j * 256;
    int row = f / 192, col = f - row * 192;
    int h = (col >= 96) ? 1 : 0, d = col - h * 96;
    size_t grow = (size_t)(b * 2 + h) * TLEN + t0 + row;
    float acc = 0.f;
    #pragma unroll
    for (int c = 0; c < SCH; ++c)
      acc += bf2f(Opart[((size_t)c * BHT + grow) * 96 + d]) * ce[row][h][c];
    #pragma unroll
    for (int dd = 0; dd < 9; ++dd)
      acc += cbx[row][h][dd] * relvS[dd * 96 + d];
    Af[row][col] = f2bf(acc * cinvL[row][h]);
  }

  f32x4 acc3[3] = {};
  for (int kc = 0; kc < CH; kc += 64) {
    __syncthreads();   // (first iter: Af/stats visible) prev MFMA done reading Bs
    #pragma unroll
    for (int j = 0; j < 6; ++j) *(u16x8*)&Bs[brr[j]][bc8[j]] = breg[j];
    if (kc + 64 < CH) {
      int kn = kc + 64;
      #pragma unroll
      for (int j = 0; j < 6; ++j)
        breg[j] = *(const u16x8*)&Bw[(size_t)brr[j] * CH + kn + bc8[j]];
    }
    __syncthreads();
    #pragma unroll
    for (int k2 = 0; k2 < 2; ++k2) {
      bf16x8 a = *(const bf16x8*)&Af[lr][kc + k2 * 32 + lg * 8];
      #pragma unroll
      for (int j = 0; j < 3; ++j) {
        bf16x8 bfr = *(const bf16x8*)&Bs[w * 48 + j * 16 + lr][k2 * 32 + lg * 8];
        acc3[j] = __builtin_amdgcn_mfma_f32_16x16x32_bf16(a, bfr, acc3[j], 0, 0, 0);
      }
    }
  }
  // epilogue: bias + residual + per-row LayerNorm
  float vv[3][4], sp[4] = {}, sp2[4] = {};
  #pragma unroll
  for (int j = 0; j < 3; ++j) {
    int col = w * 48 + j * 16 + lr;
    float bb = bias[col];
    #pragma unroll
    for (int r = 0; r < 4; ++r) {
      int row = t0 + lg * 4 + r;
      float y = acc3[j][r] + bb;
      float res = Xc[((size_t)b * TLEN + row) * CH + col];
      float t = res + y;
      vv[j][r] = t; sp[r] += t; sp2[r] += t * t;
    }
  }
  #pragma unroll
  for (int m = 1; m <= 8; m <<= 1)
    #pragma unroll
    for (int r = 0; r < 4; ++r) {
      sp[r] += __shfl_xor(sp[r], m, 64);
      sp2[r] += __shfl_xor(sp2[r], m, 64);
    }
  __syncthreads();
  if (lr == 0) {
    #pragma unroll
    for (int r = 0; r < 4; ++r) {
      sred[w][lg * 4 + r][0] = sp[r];
      sred[w][lg * 4 + r][1] = sp2[r];
    }
  }
  __syncthreads();
  #pragma unroll
  for (int r = 0; r < 4; ++r) {
    int row = lg * 4 + r;
    float s  = sred[0][row][0] + sred[1][row][0] + sred[2][row][0] + sred[3][row][0];
    float s2 = sred[0][row][1] + sred[1][row][1] + sred[2][row][1] + sred[3][row][1];
    float mean = s * (1.f / CH);
    float var = s2 * (1.f / CH) - mean * mean;
    float rs = rsqrtf(var + EPSV);
    #pragma unroll
    for (int j = 0; j < 3; ++j) {
      int col = w * 48 + j * 16 + lr;
      float o = g[col] * (vv[j][r] - mean) * rs + bt[col];
      size_t idx = ((size_t)b * TLEN + t0 + row) * CH + col;
      Xc[idx] = o; Xbf[idx] = f2bf(o);
    }
  }
}

// ---------- fused residual(f32) + bf16-y + channel LayerNorm ----------
__global__ __launch_bounds__(256) void ln_cl_kernel(
    const float* __restrict__ res, const unsigned short* __restrict__ yb,
    const float* __restrict__ g, const float* __restrict__ bt,
    float* __restrict__ Xc, unsigned short* __restrict__ Xbf)
{
  int row = blockIdx.x * 4 + (threadIdx.x >> 6);
  int lane = threadIdx.x & 63;
  const float* r = res + (size_t)row * CH;
  const unsigned short* y = yb + (size_t)row * CH;
  float v[3]; float s = 0.f, s2 = 0.f;
  #pragma unroll
  for (int j = 0; j < 3; ++j) {
    float t = r[lane + 64 * j] + bf2f(y[lane + 64 * j]);
    v[j] = t; s += t; s2 += t * t;
  }
  #pragma unroll
  for (int m = 1; m <= 32; m <<= 1) {
    s += __shfl_xor(s, m, 64);
    s2 += __shfl_xor(s2, m, 64);
  }
  float mean = s * (1.f / CH);
  float var = s2 * (1.f / CH) - mean * mean;
  float rs = rsqrtf(var + EPSV);
  #pragma unroll
  for (int j = 0; j < 3; ++j) {
    int c = lane + 64 * j;
    float o = g[c] * (v[j] - mean) * rs + bt[c];
    size_t idx = (size_t)row * CH + c;
    Xc[idx] = o; Xbf[idx] = f2bf(o);
  }
}

// ---------- flash attention partial (s-chunked, swapped-QK, base-2, dbuf, XCD-pinned) ----------
// Ps has its OWN buffer (no Ks alias) -> only 2 barriers/iter (Ps access is same-wave-only).
// LDS 38.9 KB, still 4 blocks/CU.
__global__ __launch_bounds__(256, 4) void flash_part(
    const unsigned short* __restrict__ Qg, const unsigned short* __restrict__ Kg,
    const unsigned short* __restrict__ Vg, const float* __restrict__ relk,
    unsigned short* __restrict__ Opart, float* __restrict__ mG, float* __restrict__ lG,
    float* __restrict__ bandG)
{
  __shared__ __align__(16) unsigned short KsB[64 * 104];
  __shared__ __align__(16) unsigned short QV[96 * 72];   // Qs[64][104] then Vs[96][72]
  __shared__ __align__(16) unsigned short PsB[64 * 72];
  __shared__ float qrk[64][9];
  int id = blockIdx.x;
  int bh = id & 7;                     // XCD-pinned
  int rest = id >> 3;
  int t0 = (rest & 31) * 64;
  int zc = rest >> 5;                  // chunk index 0..SCH-1
  int c0 = zc * CHUNK;
  int b = bh >> 1, h = bh & 1;
  int tid = threadIdx.x; int w = tid >> 6, lane = tid & 63;
  int lr = lane & 15, lg = lane >> 4;
  int q = w * 16 + lr;                 // this thread's softmax-state query row
  const unsigned short* Qb = Qg + (size_t)b * TLEN * CH + h * DKH;
  const unsigned short* Kb = Kg + (size_t)b * TLEN * CH + h * DKH;
  const unsigned short* Vb = Vg + ((size_t)b * CH + h * DKH) * TLEN;
  unsigned short (*Qs)[104] = (unsigned short(*)[104])QV;
  unsigned short (*Vs)[72] = (unsigned short(*)[72])QV;
  unsigned short (*Ks)[104] = (unsigned short(*)[104])KsB;
  unsigned short (*Ps)[72] = (unsigned short(*)[72])PsB;

  // staging index precompute (3 u16x8 per thread for K and for V)
  int kr[3], kc8[3], vr[3], vc8[3];
  #pragma unroll
  for (int j = 0; j < 3; ++j) {
    int f = tid + j * 256;
    kr[j] = f / 12; kc8[j] = (f % 12) * 8;
    vr[j] = f >> 3; vc8[j] = (f & 7) * 8;
  }

  for (int f = tid; f < 64 * 12; f += 256) {
    int r = f / 12, c8 = (f % 12) * 8;
    *(u16x8*)&Qs[r][c8] = *(const u16x8*)&Qb[(size_t)(t0 + r) * CH + c8];
  }
  __syncthreads();
  bool overlap = (t0 + 64 + WIN > c0) && (t0 - WIN < c0 + CHUNK);
  if (overlap) {
    for (int f = tid; f < 576; f += 256) {
      int r = f / 9, dd = f - (f / 9) * 9;
      float s = 0.f;
      #pragma unroll 8
      for (int d = 0; d < DKH; ++d) s += bf2f(Qs[r][d]) * relk[dd * DKH + d];
      qrk[r][dd] = s;    // already in base-2 domain (Q pre-scaled by log2e)
    }
  }
  bf16x8 qf[3];
  #pragma unroll
  for (int kc = 0; kc < 3; ++kc) qf[kc] = *(const bf16x8*)&Qs[q][kc * 32 + lg * 8];
  float mrow = -1e30f, lrow = 0.f;   // lrow: per-thread partial (16 cols); reduced at epilogue
  f32x4 oacc[6] = {};

  // prologue: prefetch tile 0 into registers
  u16x8 kreg[3], vreg[3];
  #pragma unroll
  for (int j = 0; j < 3; ++j)
    kreg[j] = *(const u16x8*)&Kb[(size_t)(c0 + kr[j]) * CH + kc8[j]];
  #pragma unroll
  for (int j = 0; j < 3; ++j)
    vreg[j] = *(const u16x8*)&Vb[(size_t)vr[j] * TLEN + c0 + vc8[j]];

  for (int it = 0; it < CHUNK / 64; ++it) {
    int s0 = c0 + it * 64;
    __syncthreads();                      // A: prev QK^T reads of Ks and prev PV reads of Vs done
    #pragma unroll
    for (int j = 0; j < 3; ++j) *(u16x8*)&Ks[kr[j]][kc8[j]] = kreg[j];
    #pragma unroll
    for (int j = 0; j < 3; ++j) *(u16x8*)&Vs[vr[j]][vc8[j]] = vreg[j];
    if (it + 1 < CHUNK / 64) {            // issue next tile's loads (hide under compute)
      int sn = s0 + 64;
      #pragma unroll
      for (int j = 0; j < 3; ++j)
        kreg[j] = *(const u16x8*)&Kb[(size_t)(sn + kr[j]) * CH + kc8[j]];
      #pragma unroll
      for (int j = 0; j < 3; ++j)
        vreg[j] = *(const u16x8*)&Vb[(size_t)vr[j] * TLEN + sn + vc8[j]];
    }
    __syncthreads();                      // B: Ks/Vs ready

    // S^T tile: sacc[ct][r] = S[s = ct*16+lg*4+r][q]
    f32x4 sacc[4] = {};
    __builtin_amdgcn_s_setprio(1);
    #pragma unroll
    for (int kc = 0; kc < 3; ++kc) {
      #pragma unroll
      for (int ct = 0; ct < 4; ++ct) {
        bf16x8 kfr = *(const bf16x8*)&Ks[ct * 16 + lr][kc * 32 + lg * 8];
        sacc[ct] = __builtin_amdgcn_mfma_f32_16x16x32_bf16(kfr, qf[kc], sacc[ct], 0, 0, 0);
      }
    }
    __builtin_amdgcn_s_setprio(0);
    // band bias (only on diagonal-overlapping tiles; block-uniform predicate)
    if (s0 + 64 + WIN > t0 && s0 < t0 + 64 + WIN) {
      #pragma unroll
      for (int ct = 0; ct < 4; ++ct)
        #pragma unroll
        for (int r = 0; r < 4; ++r) {
          int dlt = (s0 + ct * 16 + lg * 4 + r) - (t0 + q);
          if (dlt >= -WIN && dlt <= WIN) {
            float v = sacc[ct][r] + qrk[q][dlt + WIN];
            sacc[ct][r] = v;
            bandG[((size_t)bh * TLEN + t0 + q) * 9 + dlt + WIN] = v;  // logit, exactly-once
          }
        }
    }
    float cm[4];
    #pragma unroll
    for (int ct = 0; ct < 4; ++ct)
      cm[ct] = fmaxf(fmaxf(sacc[ct][0], sacc[ct][1]), fmaxf(sacc[ct][2], sacc[ct][3]));
    float tmax = fmaxf(fmaxf(cm[0], cm[1]), fmaxf(cm[2], cm[3]));
    tmax = fmaxf(tmax, __shfl_xor(tmax, 16, 64));
    tmax = fmaxf(tmax, __shfl_xor(tmax, 32, 64));
    // defer-rescale: skip alpha path if no q in this wave grew past mrow+8
    bool upd = !__all(tmax <= mrow + 8.f);
    float mnew = upd ? fmaxf(mrow, tmax) : mrow;
    float psum = 0.f;
    #pragma unroll
    for (int ct = 0; ct < 4; ++ct) {
      float p0 = exp2a(sacc[ct][0] - mnew), p1 = exp2a(sacc[ct][1] - mnew);
      float p2 = exp2a(sacc[ct][2] - mnew), p3 = exp2a(sacc[ct][3] - mnew);
      psum += (p0 + p1) + (p2 + p3);
      ushort4 pk;
      pk.x = f2bf(p0); pk.y = f2bf(p1); pk.z = f2bf(p2); pk.w = f2bf(p3);
      *(ushort4*)&Ps[q][ct * 16 + lg * 4] = pk;   // same-wave rows only: no barrier needed
    }
    if (upd) {
      float alpha = exp2a(mrow - mnew);      // alpha for q = w*16+lr
      lrow *= alpha;
      // oacc rows are q_out = w*16 + lg*4 + r -> need THOSE rows' alphas
      float alo[4];
      #pragma unroll
      for (int r = 0; r < 4; ++r) alo[r] = __shfl(alpha, lg * 4 + r, 64);
      #pragma unroll
      for (int dt = 0; dt < 6; ++dt)
        #pragma unroll
        for (int r = 0; r < 4; ++r) oacc[dt][r] *= alo[r];
      mrow = mnew;
    }
    lrow += psum;
    __builtin_amdgcn_s_setprio(1);
    #pragma unroll
    for (int ks = 0; ks < 2; ++ks) {
      bf16x8 pa = *(const bf16x8*)&Ps[q][ks * 32 + lg * 8];   // same-wave rows: no barrier
      #pragma unroll
      for (int dt = 0; dt < 6; ++dt) {
        bf16x8 vf = *(const bf16x8*)&Vs[dt * 16 + lr][ks * 32 + lg * 8];
        oacc[dt] = __builtin_amdgcn_mfma_f32_16x16x32_bf16(pa, vf, oacc[dt], 0, 0, 0);
      }
    }
    __builtin_amdgcn_s_setprio(0);
  }

  size_t pbase = ((size_t)zc * (BATCH * NH) + bh) * TLEN + t0;
  #pragma unroll
  for (int dt = 0; dt < 6; ++dt)
    #pragma unroll
    for (int r = 0; r < 4; ++r)
      Opart[(pbase + w * 16 + lg * 4 + r) * 96 + dt * 16 + lr] = f2bf(oacc[dt][r]);
  // reduce the deferred per-thread partial l across the 4 lanes sharing q
  float lfull = lrow;
  lfull += __shfl_xor(lfull, 16, 64);
  lfull += __shfl_xor(lfull, 32, 64);
  if (lg == 0) {
    mG[pbase + q] = mrow;
    lG[pbase + q] = lfull;
  }
}

extern "C" void kernel_launch(void* const* d_in, const int* in_sizes, int n_in,
                              void* d_out, int out_size, void* d_ws, size_t ws_size,
                              hipStream_t stream) {
  (void)in_sizes; (void)n_in; (void)out_size; (void)ws_size;
  const float* x    = (const float*)d_in[0];
  const float* mask = (const float*)d_in[1];
  const float* wq   = (const float*)d_in[2];
  const float* bq   = (const float*)d_in[3];
  const float* wk   = (const float*)d_in[4];
  const float* bk   = (const float*)d_in[5];
  const float* wv   = (const float*)d_in[6];
  const float* bv   = (const float*)d_in[7];
  const float* wo   = (const float*)d_in[8];
  const float* bo   = (const float*)d_in[9];
  const float* relk = (const float*)d_in[10];
  const float* relv = (const float*)d_in[11];
  const float* ln1g = (const float*)d_in[12];
  const float* ln1b = (const float*)d_in[13];
  const float* fw1  = (const float*)d_in[14];
  const float* fb1  = (const float*)d_in[15];
  const float* fw2  = (const float*)d_in[16];
  const float* fb2  = (const float*)d_in[17];
  const float* ln2g = (const float*)d_in[18];
  const float* ln2b = (const float*)d_in[19];

  char* p = (char*)d_ws;
  float* Xc = (float*)p;                      p += (size_t)NBCT * 4;
  unsigned short* Xbf  = (unsigned short*)p;  p += (size_t)NBCT * 2;
  unsigned short* Qbf  = (unsigned short*)p;  p += (size_t)NBCT * 2;  // K,V contiguous after Q
  unsigned short* Kbf  = (unsigned short*)p;  p += (size_t)NBCT * 2;
  unsigned short* Vbf  = (unsigned short*)p;  p += (size_t)NBCT * 2;
  char* R = p;                                p += (size_t)NBCT * 16;
  unsigned short* Opart = (unsigned short*)R;              // bf16 partials: SCH*BHT*96*2 = NBCT*8 bytes
  unsigned short* Ybf = (unsigned short*)R;                // bf16 [B][T][C], overlays dead Opart
  unsigned short* Hbf = (unsigned short*)(R + (size_t)NBCT * 2);  // disjoint from Ybf
  float* mG = (float*)p;                      p += (size_t)SCH * BHT * 4;
  float* lG = (float*)p;                      p += (size_t)SCH * BHT * 4;
  float* bandG = (float*)p;                   p += (size_t)BHT * 9 * 4;
  unsigned short* Wqkv = (unsigned short*)p;  p += (size_t)LNUM * 576 * CH * 2;
  float* Bqkv = (float*)p;                    p += (size_t)LNUM * 576 * 4;
  unsigned short* Wob  = (unsigned short*)p;  p += (size_t)LNUM * CH * CH * 2;
  unsigned short* W1b  = (unsigned short*)p;  p += (size_t)LNUM * 3 * FCH * CH * 2;
  unsigned short* W2b  = (unsigned short*)p;

  prep_all<<<2048, 256, 0, stream>>>(wq, wk, wv, bq, bk, bv, wo, fw1, fw2,
                                     Wqkv, Bqkv, Wob, W1b, W2b);
  tin_kernel<<<dim3(TLEN / 32, CH / 32, BATCH), 256, 0, stream>>>(x, mask, Xc, Xbf);

  for (int l = 0; l < LNUM; ++l) {
    gemm_tc<3, 1, 0, 1, 2><<<dim3(32, 9, 4), 256, 0, stream>>>(
        Xbf, Wqkv + (size_t)l * 576 * CH, Bqkv + l * 576, Qbf, CH, 576);
    flash_part<<<dim3(32 * 8 * SCH), 256, 0, stream>>>(
        Qbf, Kbf, Vbf, relk + (size_t)l * 9 * DKH, Opart, mG, lG, bandG);
    gemm_wolnc<<<dim3(TLEN / 16, BATCH), 256, 0, stream>>>(
        Opart, mG, lG, bandG, relv + (size_t)l * 9 * DKH,
        Wob + (size_t)l * CH * CH, bo + l * CH,
        ln1g + l * CH, ln1b + l * CH, Xc, Xbf);
    gemm_tc<0, 3, 1, 1, 2><<<dim3(32, 12, 4), 256, 0, stream>>>(
        Xbf, W1b + (size_t)l * 3 * FCH * CH, fb1 + l * FCH, Hbf, CH, FCH);
    gemm_tc<0, 3, 0, 1, 2><<<dim3(32, 3, 4), 256, 0, stream>>>(
        Hbf, W2b + (size_t)l * 3 * CH * FCH, fb2 + l * CH, Ybf, FCH, CH);
    ln_cl_kernel<<<BATCH * TLEN / 4, 256, 0, stream>>>(
        Xc, Ybf, ln2g + l * CH, ln2b + l * CH, Xc, Xbf);
  }
  tout_kernel<<<dim3(TLEN / 32, CH / 32, BATCH), 256, 0, stream>>>(Xc, mask, (float*)d_out);
}

// Round 20
// 578.283 us; speedup vs baseline: 1.0327x; 1.0121x over previous
//
#include <hip/hip_runtime.h>

#define LNUM 6
#define CH 192
#define FCH 768
#define NH 2
#define DKH 96
#define WIN 4
#define BATCH 4
#define TLEN 2048
#define EPSV 1e-5f
#define SCH 4
#define CHUNK (TLEN / SCH)
#define NBCT (BATCH*CH*TLEN)
#define NBFT (BATCH*FCH*TLEN)
#define BHT (BATCH*NH*TLEN)    // 16384

typedef __attribute__((ext_vector_type(8))) short bf16x8;
typedef __attribute__((ext_vector_type(4))) float f32x4;
typedef __attribute__((ext_vector_type(8))) unsigned short u16x8;

__device__ __forceinline__ unsigned short f2bf(float f) {
  unsigned int u = __builtin_bit_cast(unsigned int, f);
  u = (u + 0x7fffu + ((u >> 16) & 1u)) >> 16;
  return (unsigned short)u;
}
__device__ __forceinline__ float bf2f(unsigned short s) {
  return __builtin_bit_cast(float, ((unsigned int)s) << 16);
}
__device__ __forceinline__ float exp2a(float x) {   // hardware 2^x, hazard-safe
#if __has_builtin(__builtin_amdgcn_exp2f)
  return __builtin_amdgcn_exp2f(x);
#else
  return exp2f(x);
#endif
}

// ---------- fused weight prep (QKV fuse+scale, WO cvt, FFN w1/w2 transpose) ----------
__global__ __launch_bounds__(256) void prep_all(
    const float* __restrict__ wq, const float* __restrict__ wk, const float* __restrict__ wv,
    const float* __restrict__ bq, const float* __restrict__ bk, const float* __restrict__ bv,
    const float* __restrict__ wo, const float* __restrict__ fw1, const float* __restrict__ fw2,
    unsigned short* __restrict__ Wqkv, float* __restrict__ Bqkv,
    unsigned short* __restrict__ Wob, unsigned short* __restrict__ W1b,
    unsigned short* __restrict__ W2b)
{
  const float qscale = 0.10206207261596575f * 1.4426950408889634f;  // dk^-0.5 * log2(e)
  const int n0 = LNUM * 576 * CH;            // qkv
  const int n1 = LNUM * CH * CH;             // wo
  const int n2 = LNUM * 3 * FCH * CH;        // w1
  const int n3 = LNUM * 3 * CH * FCH;        // w2
  int total = n0 + n1 + n2 + n3;
  for (int i = blockIdx.x * 256 + threadIdx.x; i < total; i += gridDim.x * 256) {
    if (i < n0) {
      int c = i % CH; int n = (i / CH) % 576; int l = i / (CH * 576);
      float sc = (n < 192) ? qscale : 1.f;
      const float* src = (n < 192) ? wq : (n < 384) ? wk : wv;
      int nn = n % 192;
      Wqkv[i] = f2bf(src[((size_t)l * CH + nn) * CH + c] * sc);
      if (c == 0) {
        const float* bs = (n < 192) ? bq : (n < 384) ? bk : bv;
        Bqkv[l * 576 + n] = bs[l * CH + nn] * sc;
      }
    } else if (i < n0 + n1) {
      int j = i - n0;
      Wob[j] = f2bf(wo[j]);
    } else if (i < n0 + n1 + n2) {
      int j = i - n0 - n1;           // dst [L][3][FCH][CH]
      int c = j % CH; int t1 = j / CH;
      int f = t1 % FCH; int t2 = t1 / FCH;
      int kk = t2 % 3; int l = t2 / 3;
      W1b[j] = f2bf(fw1[(((size_t)l * FCH + f) * CH + c) * 3 + kk]);
    } else {
      int j = i - n0 - n1 - n2;      // dst [L][3][CH][FCH]
      int c = j % FCH; int t1 = j / FCH;
      int f = t1 % CH; int t2 = t1 / CH;
      int kk = t2 % 3; int l = t2 / 3;
      W2b[j] = f2bf(fw2[(((size_t)l * CH + f) * FCH + c) * 3 + kk]);
    }
  }
}

// ---------- transpose in/out (bf16 activation only) ----------
__global__ __launch_bounds__(256) void tin_kernel(const float* __restrict__ x,
    const float* __restrict__ mask, unsigned short* __restrict__ Xbf) {
  __shared__ float ls[32][33];
  int b = blockIdx.z; int c0 = blockIdx.y * 32, t0 = blockIdx.x * 32;
  int tx = threadIdx.x & 31, ty = threadIdx.x >> 5;
  #pragma unroll
  for (int j = 0; j < 4; ++j)
    ls[ty + j * 8][tx] = x[((size_t)b * CH + c0 + ty + j * 8) * TLEN + t0 + tx];
  __syncthreads();
  #pragma unroll
  for (int j = 0; j < 4; ++j) {
    int t = t0 + ty + j * 8;
    float v = ls[tx][ty + j * 8] * mask[b * TLEN + t];
    Xbf[((size_t)b * TLEN + t) * CH + c0 + tx] = f2bf(v);
  }
}

__global__ __launch_bounds__(256) void tout_kernel(const unsigned short* __restrict__ Xbf,
    const float* __restrict__ mask, float* __restrict__ out) {
  __shared__ float ls[32][33];
  int b = blockIdx.z; int c0 = blockIdx.y * 32, t0 = blockIdx.x * 32;
  int tx = threadIdx.x & 31, ty = threadIdx.x >> 5;
  #pragma unroll
  for (int j = 0; j < 4; ++j)
    ls[ty + j * 8][tx] = bf2f(Xbf[((size_t)b * TLEN + t0 + ty + j * 8) * CH + c0 + tx]);
  __syncthreads();
  #pragma unroll
  for (int j = 0; j < 4; ++j)
    out[((size_t)b * CH + c0 + ty + j * 8) * TLEN + t0 + tx] =
        ls[tx][ty + j * 8] * mask[b * TLEN + t0 + tx];
}

// ---------- generic MFMA GEMM, BK=64, M-tile = MFR*32, reg-prefetch pipelined ----------
// OUTMODE: 0=bf16 [B][T][N], 3=QKV fused epilogue
template<int OUTMODE, int NSHIFT, int RELU, int KSPLIT, int MFR>
__global__ __launch_bounds__(256) void gemm_tc(
    const unsigned short* __restrict__ A, const unsigned short* __restrict__ Bw,
    const float* __restrict__ bias, void* __restrict__ Y, int Cin, int N)
{
  constexpr int HALO = (NSHIFT == 3) ? 1 : 0;
  constexpr int AROWS = MFR * 32 + 2 * HALO;
  constexpr int ACH = (AROWS * 8 + 255) / 256;       // per-thread A-stage chunks
  constexpr int BCH = (NSHIFT * 64 * 8) / 256;       // per-thread B-stage chunks (exact)
  __shared__ __align__(16) unsigned short As[AROWS][72];
  __shared__ __align__(16) unsigned short Bs[NSHIFT][64][72];
  int zz = blockIdx.z;
  int b = zz / KSPLIT, ks = zz % KSPLIT;
  int t0 = blockIdx.x * (MFR * 32), n0 = blockIdx.y * 64;
  int tid = threadIdx.x;
  int w = tid >> 6, lane = tid & 63;
  int wr = w >> 1, wc = w & 1;
  int lr = lane & 15, lg = lane >> 4;
  const unsigned short* Ab = A + (size_t)b * TLEN * Cin;
  int klen = Cin / KSPLIT, k0 = ks * klen;

  // loop-invariant staging indices
  int ar[ACH], ac8[ACH]; bool aok[ACH], ain[ACH];
  #pragma unroll
  for (int j = 0; j < ACH; ++j) {
    int f = tid + j * 256;
    ar[j] = f >> 3; ac8[j] = (f & 7) * 8;
    aok[j] = (f < AROWS * 8);
    int tg = t0 - HALO + ar[j];
    ain[j] = aok[j] && (!HALO || (tg >= 0 && tg < TLEN));
  }
  int brr[BCH], bkk[BCH], bc8[BCH];
  #pragma unroll
  for (int j = 0; j < BCH; ++j) {
    int f = tid + j * 256;
    bkk[j] = f >> 9; brr[j] = (f >> 3) & 63; bc8[j] = (f & 7) * 8;
  }

  u16x8 areg[ACH], breg[BCH];
  f32x4 acc[MFR][2] = {};

  // prologue: load first K-step into registers
  #pragma unroll
  for (int j = 0; j < ACH; ++j) {
    u16x8 v = {};
    if (ain[j]) v = *(const u16x8*)&Ab[(size_t)(t0 - HALO + ar[j]) * Cin + k0 + ac8[j]];
    areg[j] = v;
  }
  #pragma unroll
  for (int j = 0; j < BCH; ++j)
    breg[j] = *(const u16x8*)&Bw[((size_t)bkk[j] * N + n0 + brr[j]) * Cin + k0 + bc8[j]];

  for (int kc = k0; kc < k0 + klen; kc += 64) {
    __syncthreads();     // previous MFMA phase done reading LDS
    #pragma unroll
    for (int j = 0; j < ACH; ++j)
      if (aok[j]) *(u16x8*)&As[ar[j]][ac8[j]] = areg[j];
    #pragma unroll
    for (int j = 0; j < BCH; ++j)
      *(u16x8*)&Bs[bkk[j]][brr[j]][bc8[j]] = breg[j];
    if (kc + 64 < k0 + klen) {   // issue next K-step's loads; latency hides under MFMA
      int kn = kc + 64;
      #pragma unroll
      for (int j = 0; j < ACH; ++j) {
        u16x8 v = {};
        if (ain[j]) v = *(const u16x8*)&Ab[(size_t)(t0 - HALO + ar[j]) * Cin + kn + ac8[j]];
        areg[j] = v;
      }
      #pragma unroll
      for (int j = 0; j < BCH; ++j)
        breg[j] = *(const u16x8*)&Bw[((size_t)bkk[j] * N + n0 + brr[j]) * Cin + kn + bc8[j]];
    }
    __syncthreads();
    #pragma unroll
    for (int kk = 0; kk < NSHIFT; ++kk) {
      #pragma unroll
      for (int k2 = 0; k2 < 2; ++k2) {
        bf16x8 b0 = *(const bf16x8*)&Bs[kk][wc * 32 + lr][k2 * 32 + lg * 8];
        bf16x8 b1 = *(const bf16x8*)&Bs[kk][wc * 32 + 16 + lr][k2 * 32 + lg * 8];
        #pragma unroll
        for (int i = 0; i < MFR; ++i) {
          bf16x8 a = *(const bf16x8*)&As[wr * MFR * 16 + i * 16 + lr + kk][k2 * 32 + lg * 8];
          acc[i][0] = __builtin_amdgcn_mfma_f32_16x16x32_bf16(a, b0, acc[i][0], 0, 0, 0);
          acc[i][1] = __builtin_amdgcn_mfma_f32_16x16x32_bf16(a, b1, acc[i][1], 0, 0, 0);
        }
      }
    }
  }
  #pragma unroll
  for (int i = 0; i < MFR; ++i) {
    #pragma unroll
    for (int j = 0; j < 2; ++j) {
      int n = n0 + wc * 32 + j * 16 + lr;
      float bb = (ks == 0) ? bias[n] : 0.f;
      float vals[4];
      #pragma unroll
      for (int r = 0; r < 4; ++r) {
        float v = acc[i][j][r] + bb;
        if (RELU) v = fmaxf(v, 0.f);
        vals[r] = v;
      }
      int trow = t0 + wr * MFR * 16 + i * 16 + lg * 4;
      if (OUTMODE == 0) {
        unsigned short* Yp = (unsigned short*)Y + ((size_t)b * TLEN + trow) * N + n;
        #pragma unroll
        for (int r = 0; r < 4; ++r) Yp[(size_t)r * N] = f2bf(vals[r]);
      } else {  // QKV fused: n tile uniform within one of Q/K/V
        unsigned short* base = (unsigned short*)Y;
        if (n0 < 192) {
          unsigned short* Yp = base + ((size_t)b * TLEN + trow) * CH + n;
          #pragma unroll
          for (int r = 0; r < 4; ++r) Yp[(size_t)r * CH] = f2bf(vals[r]);
        } else if (n0 < 384) {
          unsigned short* Yp = base + (size_t)NBCT + ((size_t)b * TLEN + trow) * CH + (n - 192);
          #pragma unroll
          for (int r = 0; r < 4; ++r) Yp[(size_t)r * CH] = f2bf(vals[r]);
        } else {
          ushort4 pk;
          pk.x = f2bf(vals[0]); pk.y = f2bf(vals[1]); pk.z = f2bf(vals[2]); pk.w = f2bf(vals[3]);
          *(ushort4*)(base + 2 * (size_t)NBCT + ((size_t)b * CH + (n - 384)) * TLEN + trow) = pk;
        }
      }
    }
  }
}

// ---------- fused flash-combine + WO GEMM + residual(bf16) + LayerNorm ----------
__global__ __launch_bounds__(256) void gemm_wolnc(
    const unsigned short* __restrict__ Opart, const float* __restrict__ mG,
    const float* __restrict__ lG, const float* __restrict__ bandG,
    const float* __restrict__ relv,
    const unsigned short* __restrict__ Bw, const float* __restrict__ bias,
    const float* __restrict__ g, const float* __restrict__ bt,
    unsigned short* __restrict__ Xbf)
{
  __shared__ __align__(16) unsigned short Af[16][200];  // AO tile, full K=192
  __shared__ __align__(16) unsigned short Bs[192][72];
  __shared__ float sred[4][16][2];
  __shared__ float ce[16][2][4];
  __shared__ float cinvL[16][2];
  __shared__ float cbx[16][2][9];
  __shared__ float relvS[9 * 96];
  int b = blockIdx.y;
  int t0 = blockIdx.x * 16;
  int tid = threadIdx.x;
  int w = tid >> 6, lane = tid & 63;
  int lr = lane & 15, lg = lane >> 4;
  int brr[6], bc8[6];
  #pragma unroll
  for (int j = 0; j < 6; ++j) { int f = tid + j * 256; brr[j] = f >> 3; bc8[j] = (f & 7) * 8; }

  u16x8 breg[6];
  #pragma unroll
  for (int j = 0; j < 6; ++j)
    breg[j] = *(const u16x8*)&Bw[(size_t)brr[j] * CH + bc8[j]];

  for (int f = tid; f < 864; f += 256) relvS[f] = relv[f];
  if (tid < 32) {   // per-(row,head) combine stats
    int r = tid >> 1, h = tid & 1;
    int t = t0 + r;
    size_t grow = (size_t)(b * 2 + h) * TLEN + t;
    float mv[SCH], lv[SCH], m = -1e30f;
    #pragma unroll
    for (int c = 0; c < SCH; ++c) {
      mv[c] = mG[(size_t)c * BHT + grow];
      lv[c] = lG[(size_t)c * BHT + grow];
      m = fmaxf(m, mv[c]);
    }
    float L = 0.f;
    #pragma unroll
    for (int c = 0; c < SCH; ++c) {
      float e = exp2a(mv[c] - m);
      ce[r][h][c] = e; L += lv[c] * e;
    }
    cinvL[r][h] = 1.f / L;
    #pragma unroll
    for (int dd = 0; dd < 9; ++dd) {
      int s = t + dd - WIN;
      cbx[r][h][dd] = (s >= 0 && s < TLEN) ? exp2a(bandG[grow * 9 + dd] - m) : 0.f;
    }
  }
  __syncthreads();
  // build AO tile into Af
  #pragma unroll
  for (int j = 0; j < 12; ++j) {
    int f = tid + j * 256;
    int row = f / 192, col = f - row * 192;
    int h = (col >= 96) ? 1 : 0, d = col - h * 96;
    size_t grow = (size_t)(b * 2 + h) * TLEN + t0 + row;
    float acc = 0.f;
    #pragma unroll
    for (int c = 0; c < SCH; ++c)
      acc += bf2f(Opart[((size_t)c * BHT + grow) * 96 + d]) * ce[row][h][c];
    #pragma unroll
    for (int dd = 0; dd < 9; ++dd)
      acc += cbx[row][h][dd] * relvS[dd * 96 + d];
    Af[row][col] = f2bf(acc * cinvL[row][h]);
  }

  f32x4 acc3[3] = {};
  for (int kc = 0; kc < CH; kc += 64) {
    __syncthreads();   // (first iter: Af/stats visible) prev MFMA done reading Bs
    #pragma unroll
    for (int j = 0; j < 6; ++j) *(u16x8*)&Bs[brr[j]][bc8[j]] = breg[j];
    if (kc + 64 < CH) {
      int kn = kc + 64;
      #pragma unroll
      for (int j = 0; j < 6; ++j)
        breg[j] = *(const u16x8*)&Bw[(size_t)brr[j] * CH + kn + bc8[j]];
    }
    __syncthreads();
    #pragma unroll
    for (int k2 = 0; k2 < 2; ++k2) {
      bf16x8 a = *(const bf16x8*)&Af[lr][kc + k2 * 32 + lg * 8];
      #pragma unroll
      for (int j = 0; j < 3; ++j) {
        bf16x8 bfr = *(const bf16x8*)&Bs[w * 48 + j * 16 + lr][k2 * 32 + lg * 8];
        acc3[j] = __builtin_amdgcn_mfma_f32_16x16x32_bf16(a, bfr, acc3[j], 0, 0, 0);
      }
    }
  }
  // epilogue: bias + residual(bf16) + per-row LayerNorm
  float vv[3][4], sp[4] = {}, sp2[4] = {};
  #pragma unroll
  for (int j = 0; j < 3; ++j) {
    int col = w * 48 + j * 16 + lr;
    float bb = bias[col];
    #pragma unroll
    for (int r = 0; r < 4; ++r) {
      int row = t0 + lg * 4 + r;
      float y = acc3[j][r] + bb;
      float res = bf2f(Xbf[((size_t)b * TLEN + row) * CH + col]);
      float t = res + y;
      vv[j][r] = t; sp[r] += t; sp2[r] += t * t;
    }
  }
  #pragma unroll
  for (int m = 1; m <= 8; m <<= 1)
    #pragma unroll
    for (int r = 0; r < 4; ++r) {
      sp[r] += __shfl_xor(sp[r], m, 64);
      sp2[r] += __shfl_xor(sp2[r], m, 64);
    }
  __syncthreads();
  if (lr == 0) {
    #pragma unroll
    for (int r = 0; r < 4; ++r) {
      sred[w][lg * 4 + r][0] = sp[r];
      sred[w][lg * 4 + r][1] = sp2[r];
    }
  }
  __syncthreads();
  #pragma unroll
  for (int r = 0; r < 4; ++r) {
    int row = lg * 4 + r;
    float s  = sred[0][row][0] + sred[1][row][0] + sred[2][row][0] + sred[3][row][0];
    float s2 = sred[0][row][1] + sred[1][row][1] + sred[2][row][1] + sred[3][row][1];
    float mean = s * (1.f / CH);
    float var = s2 * (1.f / CH) - mean * mean;
    float rs = rsqrtf(var + EPSV);
    #pragma unroll
    for (int j = 0; j < 3; ++j) {
      int col = w * 48 + j * 16 + lr;
      float o = g[col] * (vv[j][r] - mean) * rs + bt[col];
      Xbf[((size_t)b * TLEN + t0 + row) * CH + col] = f2bf(o);
    }
  }
}

// ---------- fused residual(bf16) + bf16-y + channel LayerNorm ----------
__global__ __launch_bounds__(256) void ln_cl_kernel(
    unsigned short* __restrict__ Xbf, const unsigned short* __restrict__ yb,
    const float* __restrict__ g, const float* __restrict__ bt)
{
  int row = blockIdx.x * 4 + (threadIdx.x >> 6);
  int lane = threadIdx.x & 63;
  unsigned short* r = Xbf + (size_t)row * CH;
  const unsigned short* y = yb + (size_t)row * CH;
  float v[3]; float s = 0.f, s2 = 0.f;
  #pragma unroll
  for (int j = 0; j < 3; ++j) {
    float t = bf2f(r[lane + 64 * j]) + bf2f(y[lane + 64 * j]);
    v[j] = t; s += t; s2 += t * t;
  }
  #pragma unroll
  for (int m = 1; m <= 32; m <<= 1) {
    s += __shfl_xor(s, m, 64);
    s2 += __shfl_xor(s2, m, 64);
  }
  float mean = s * (1.f / CH);
  float var = s2 * (1.f / CH) - mean * mean;
  float rs = rsqrtf(var + EPSV);
  #pragma unroll
  for (int j = 0; j < 3; ++j) {
    int c = lane + 64 * j;
    float o = g[c] * (v[j] - mean) * rs + bt[c];
    r[c] = f2bf(o);
  }
}

// ---------- flash attention partial (s-chunked, swapped-QK, base-2, dbuf, XCD-pinned) ----------
// Ps own buffer, 2 barriers/iter. LDS 38.9 KB.
__global__ __launch_bounds__(256, 4) void flash_part(
    const unsigned short* __restrict__ Qg, const unsigned short* __restrict__ Kg,
    const unsigned short* __restrict__ Vg, const float* __restrict__ relk,
    unsigned short* __restrict__ Opart, float* __restrict__ mG, float* __restrict__ lG,
    float* __restrict__ bandG)
{
  __shared__ __align__(16) unsigned short KsB[64 * 104];
  __shared__ __align__(16) unsigned short QV[96 * 72];   // Qs[64][104] then Vs[96][72]
  __shared__ __align__(16) unsigned short PsB[64 * 72];
  __shared__ float qrk[64][9];
  int id = blockIdx.x;
  int bh = id & 7;                     // XCD-pinned
  int rest = id >> 3;
  int t0 = (rest & 31) * 64;
  int zc = rest >> 5;                  // chunk index 0..SCH-1
  int c0 = zc * CHUNK;
  int b = bh >> 1, h = bh & 1;
  int tid = threadIdx.x; int w = tid >> 6, lane = tid & 63;
  int lr = lane & 15, lg = lane >> 4;
  int q = w * 16 + lr;                 // this thread's softmax-state query row
  const unsigned short* Qb = Qg + (size_t)b * TLEN * CH + h * DKH;
  const unsigned short* Kb = Kg + (size_t)b * TLEN * CH + h * DKH;
  const unsigned short* Vb = Vg + ((size_t)b * CH + h * DKH) * TLEN;
  unsigned short (*Qs)[104] = (unsigned short(*)[104])QV;
  unsigned short (*Vs)[72] = (unsigned short(*)[72])QV;
  unsigned short (*Ks)[104] = (unsigned short(*)[104])KsB;
  unsigned short (*Ps)[72] = (unsigned short(*)[72])PsB;

  // staging index precompute (3 u16x8 per thread for K and for V)
  int kr[3], kc8[3], vr[3], vc8[3];
  #pragma unroll
  for (int j = 0; j < 3; ++j) {
    int f = tid + j * 256;
    kr[j] = f / 12; kc8[j] = (f % 12) * 8;
    vr[j] = f >> 3; vc8[j] = (f & 7) * 8;
  }

  for (int f = tid; f < 64 * 12; f += 256) {
    int r = f / 12, c8 = (f % 12) * 8;
    *(u16x8*)&Qs[r][c8] = *(const u16x8*)&Qb[(size_t)(t0 + r) * CH + c8];
  }
  __syncthreads();
  bool overlap = (t0 + 64 + WIN > c0) && (t0 - WIN < c0 + CHUNK);
  if (overlap) {
    for (int f = tid; f < 576; f += 256) {
      int r = f / 9, dd = f - (f / 9) * 9;
      float s = 0.f;
      #pragma unroll 8
      for (int d = 0; d < DKH; ++d) s += bf2f(Qs[r][d]) * relk[dd * DKH + d];
      qrk[r][dd] = s;    // already in base-2 domain (Q pre-scaled by log2e)
    }
  }
  bf16x8 qf[3];
  #pragma unroll
  for (int kc = 0; kc < 3; ++kc) qf[kc] = *(const bf16x8*)&Qs[q][kc * 32 + lg * 8];
  float mrow = -1e30f, lrow = 0.f;   // lrow: per-thread partial (16 cols); reduced at epilogue
  f32x4 oacc[6] = {};

  // prologue: prefetch tile 0 into registers
  u16x8 kreg[3], vreg[3];
  #pragma unroll
  for (int j = 0; j < 3; ++j)
    kreg[j] = *(const u16x8*)&Kb[(size_t)(c0 + kr[j]) * CH + kc8[j]];
  #pragma unroll
  for (int j = 0; j < 3; ++j)
    vreg[j] = *(const u16x8*)&Vb[(size_t)vr[j] * TLEN + c0 + vc8[j]];

  for (int it = 0; it < CHUNK / 64; ++it) {
    int s0 = c0 + it * 64;
    __syncthreads();                      // A: prev QK^T reads of Ks and prev PV reads of Vs done
    #pragma unroll
    for (int j = 0; j < 3; ++j) *(u16x8*)&Ks[kr[j]][kc8[j]] = kreg[j];
    #pragma unroll
    for (int j = 0; j < 3; ++j) *(u16x8*)&Vs[vr[j]][vc8[j]] = vreg[j];
    if (it + 1 < CHUNK / 64) {            // issue next tile's loads (hide under compute)
      int sn = s0 + 64;
      #pragma unroll
      for (int j = 0; j < 3; ++j)
        kreg[j] = *(const u16x8*)&Kb[(size_t)(sn + kr[j]) * CH + kc8[j]];
      #pragma unroll
      for (int j = 0; j < 3; ++j)
        vreg[j] = *(const u16x8*)&Vb[(size_t)vr[j] * TLEN + sn + vc8[j]];
    }
    __syncthreads();                      // B: Ks/Vs ready

    // S^T tile: sacc[ct][r] = S[s = ct*16+lg*4+r][q]
    f32x4 sacc[4] = {};
    __builtin_amdgcn_s_setprio(1);
    #pragma unroll
    for (int kc = 0; kc < 3; ++kc) {
      #pragma unroll
      for (int ct = 0; ct < 4; ++ct) {
        bf16x8 kfr = *(const bf16x8*)&Ks[ct * 16 + lr][kc * 32 + lg * 8];
        sacc[ct] = __builtin_amdgcn_mfma_f32_16x16x32_bf16(kfr, qf[kc], sacc[ct], 0, 0, 0);
      }
    }
    __builtin_amdgcn_s_setprio(0);
    // band bias (only on diagonal-overlapping tiles; block-uniform predicate)
    if (s0 + 64 + WIN > t0 && s0 < t0 + 64 + WIN) {
      #pragma unroll
      for (int ct = 0; ct < 4; ++ct)
        #pragma unroll
        for (int r = 0; r < 4; ++r) {
          int dlt = (s0 + ct * 16 + lg * 4 + r) - (t0 + q);
          if (dlt >= -WIN && dlt <= WIN) {
            float v = sacc[ct][r] + qrk[q][dlt + WIN];
            sacc[ct][r] = v;
            bandG[((size_t)bh * TLEN + t0 + q) * 9 + dlt + WIN] = v;  // logit, exactly-once
          }
        }
    }
    float cm[4];
    #pragma unroll
    for (int ct = 0; ct < 4; ++ct)
      cm[ct] = fmaxf(fmaxf(sacc[ct][0], sacc[ct][1]), fmaxf(sacc[ct][2], sacc[ct][3]));
    float tmax = fmaxf(fmaxf(cm[0], cm[1]), fmaxf(cm[2], cm[3]));
    tmax = fmaxf(tmax, __shfl_xor(tmax, 16, 64));
    tmax = fmaxf(tmax, __shfl_xor(tmax, 32, 64));
    // defer-rescale: skip alpha path if no q in this wave grew past mrow+8
    bool upd = !__all(tmax <= mrow + 8.f);
    float mnew = upd ? fmaxf(mrow, tmax) : mrow;
    float psum = 0.f;
    #pragma unroll
    for (int ct = 0; ct < 4; ++ct) {
      float p0 = exp2a(sacc[ct][0] - mnew), p1 = exp2a(sacc[ct][1] - mnew);
      float p2 = exp2a(sacc[ct][2] - mnew), p3 = exp2a(sacc[ct][3] - mnew);
      psum += (p0 + p1) + (p2 + p3);
      ushort4 pk;
      pk.x = f2bf(p0); pk.y = f2bf(p1); pk.z = f2bf(p2); pk.w = f2bf(p3);
      *(ushort4*)&Ps[q][ct * 16 + lg * 4] = pk;   // same-wave rows only: no barrier needed
    }
    if (upd) {
      float alpha = exp2a(mrow - mnew);      // alpha for q = w*16+lr
      lrow *= alpha;
      // oacc rows are q_out = w*16 + lg*4 + r -> need THOSE rows' alphas
      float alo[4];
      #pragma unroll
      for (int r = 0; r < 4; ++r) alo[r] = __shfl(alpha, lg * 4 + r, 64);
      #pragma unroll
      for (int dt = 0; dt < 6; ++dt)
        #pragma unroll
        for (int r = 0; r < 4; ++r) oacc[dt][r] *= alo[r];
      mrow = mnew;
    }
    lrow += psum;
    __builtin_amdgcn_s_setprio(1);
    #pragma unroll
    for (int ks = 0; ks < 2; ++ks) {
      bf16x8 pa = *(const bf16x8*)&Ps[q][ks * 32 + lg * 8];   // same-wave rows: no barrier
      #pragma unroll
      for (int dt = 0; dt < 6; ++dt) {
        bf16x8 vf = *(const bf16x8*)&Vs[dt * 16 + lr][ks * 32 + lg * 8];
        oacc[dt] = __builtin_amdgcn_mfma_f32_16x16x32_bf16(pa, vf, oacc[dt], 0, 0, 0);
      }
    }
    __builtin_amdgcn_s_setprio(0);
  }

  size_t pbase = ((size_t)zc * (BATCH * NH) + bh) * TLEN + t0;
  #pragma unroll
  for (int dt = 0; dt < 6; ++dt)
    #pragma unroll
    for (int r = 0; r < 4; ++r)
      Opart[(pbase + w * 16 + lg * 4 + r) * 96 + dt * 16 + lr] = f2bf(oacc[dt][r]);
  // reduce the deferred per-thread partial l across the 4 lanes sharing q
  float lfull = lrow;
  lfull += __shfl_xor(lfull, 16, 64);
  lfull += __shfl_xor(lfull, 32, 64);
  if (lg == 0) {
    mG[pbase + q] = mrow;
    lG[pbase + q] = lfull;
  }
}

extern "C" void kernel_launch(void* const* d_in, const int* in_sizes, int n_in,
                              void* d_out, int out_size, void* d_ws, size_t ws_size,
                              hipStream_t stream) {
  (void)in_sizes; (void)n_in; (void)out_size; (void)ws_size;
  const float* x    = (const float*)d_in[0];
  const float* mask = (const float*)d_in[1];
  const float* wq   = (const float*)d_in[2];
  const float* bq   = (const float*)d_in[3];
  const float* wk   = (const float*)d_in[4];
  const float* bk   = (const float*)d_in[5];
  const float* wv   = (const float*)d_in[6];
  const float* bv   = (const float*)d_in[7];
  const float* wo   = (const float*)d_in[8];
  const float* bo   = (const float*)d_in[9];
  const float* relk = (const float*)d_in[10];
  const float* relv = (const float*)d_in[11];
  const float* ln1g = (const float*)d_in[12];
  const float* ln1b = (const float*)d_in[13];
  const float* fw1  = (const float*)d_in[14];
  const float* fb1  = (const float*)d_in[15];
  const float* fw2  = (const float*)d_in[16];
  const float* fb2  = (const float*)d_in[17];
  const float* ln2g = (const float*)d_in[18];
  const float* ln2b = (const float*)d_in[19];

  char* p = (char*)d_ws;
  unsigned short* Xbf  = (unsigned short*)p;  p += (size_t)NBCT * 2;
  unsigned short* Qbf  = (unsigned short*)p;  p += (size_t)NBCT * 2;  // K,V contiguous after Q
  unsigned short* Kbf  = (unsigned short*)p;  p += (size_t)NBCT * 2;
  unsigned short* Vbf  = (unsigned short*)p;  p += (size_t)NBCT * 2;
  char* R = p;                                p += (size_t)NBCT * 16;
  unsigned short* Opart = (unsigned short*)R;              // bf16 partials: SCH*BHT*96*2 = NBCT*8 bytes
  unsigned short* Ybf = (unsigned short*)R;                // bf16 [B][T][C], overlays dead Opart
  unsigned short* Hbf = (unsigned short*)(R + (size_t)NBCT * 2);  // disjoint from Ybf
  float* mG = (float*)p;                      p += (size_t)SCH * BHT * 4;
  float* lG = (float*)p;                      p += (size_t)SCH * BHT * 4;
  float* bandG = (float*)p;                   p += (size_t)BHT * 9 * 4;
  unsigned short* Wqkv = (unsigned short*)p;  p += (size_t)LNUM * 576 * CH * 2;
  float* Bqkv = (float*)p;                    p += (size_t)LNUM * 576 * 4;
  unsigned short* Wob  = (unsigned short*)p;  p += (size_t)LNUM * CH * CH * 2;
  unsigned short* W1b  = (unsigned short*)p;  p += (size_t)LNUM * 3 * FCH * CH * 2;
  unsigned short* W2b  = (unsigned short*)p;

  prep_all<<<2048, 256, 0, stream>>>(wq, wk, wv, bq, bk, bv, wo, fw1, fw2,
                                     Wqkv, Bqkv, Wob, W1b, W2b);
  tin_kernel<<<dim3(TLEN / 32, CH / 32, BATCH), 256, 0, stream>>>(x, mask, Xbf);

  for (int l = 0; l < LNUM; ++l) {
    gemm_tc<3, 1, 0, 1, 2><<<dim3(32, 9, 4), 256, 0, stream>>>(
        Xbf, Wqkv + (size_t)l * 576 * CH, Bqkv + l * 576, Qbf, CH, 576);
    flash_part<<<dim3(32 * 8 * SCH), 256, 0, stream>>>(
        Qbf, Kbf, Vbf, relk + (size_t)l * 9 * DKH, Opart, mG, lG, bandG);
    gemm_wolnc<<<dim3(TLEN / 16, BATCH), 256, 0, stream>>>(
        Opart, mG, lG, bandG, relv + (size_t)l * 9 * DKH,
        Wob + (size_t)l * CH * CH, bo + l * CH,
        ln1g + l * CH, ln1b + l * CH, Xbf);
    gemm_tc<0, 3, 1, 1, 2><<<dim3(32, 12, 4), 256, 0, stream>>>(
        Xbf, W1b + (size_t)l * 3 * FCH * CH, fb1 + l * FCH, Hbf, CH, FCH);
    gemm_tc<0, 3, 0, 1, 2><<<dim3(32, 3, 4), 256, 0, stream>>>(
        Hbf, W2b + (size_t)l * 3 * CH * FCH, fb2 + l * CH, Ybf, FCH, CH);
    ln_cl_kernel<<<BATCH * TLEN / 4, 256, 0, stream>>>(
        Xbf, Ybf, ln2g + l * CH, ln2b + l * CH);
  }
  tout_kernel<<<dim3(TLEN / 32, CH / 32, BATCH), 256, 0, stream>>>(Xbf, mask, (float*)d_out);
}